// Round 1
// baseline (1682.272 us; speedup 1.0000x reference)
//
#include <hip/hip_runtime.h>
#include <cstdint>
#include <cstddef>

// Problem constants (fixed by the reference file)
#define DIM    384
#define HEADS  6
#define HD     64
#define NTOK   15768
#define NMID   1728
#define BATCH  2
#define ROWS   (BATCH*NTOK)   // 31536
#define L1START 13824         // 8*NMID
#define L2START 15552         // 9*NMID
#define HID    96

__device__ __forceinline__ float wave_sum(float v){
  #pragma unroll
  for (int o = 32; o; o >>= 1) v += __shfl_xor(v, o, 64);
  return v;
}

// LayerNorm over 384 channels held as 6 regs/lane (c = j*64 + lane)
__device__ __forceinline__ void ln384(const float* x, float* y,
                                      const float* __restrict__ w,
                                      const float* __restrict__ b, int lane){
  float s = 0.f;
  #pragma unroll
  for (int j = 0; j < 6; j++) s += x[j];
  s = wave_sum(s);
  float m = s * (1.f/384.f);
  float v = 0.f;
  #pragma unroll
  for (int j = 0; j < 6; j++){ float d = x[j] - m; v += d*d; }
  v = wave_sum(v) * (1.f/384.f);
  float rs = rsqrtf(v + 1e-6f);
  #pragma unroll
  for (int j = 0; j < 6; j++){
    int c = j*64 + lane;
    y[j] = (x[j] - m) * rs * w[c] + b[c];
  }
}

// q = query (+feat on mid segment); qn=LN(q,qnorm); aq=LN(qn,ext_q); af=LN(LN(q,fnorm),ext_f)
__global__ void k_ln_front(const float* __restrict__ query, const float* __restrict__ feat,
                           const float* __restrict__ qw,  const float* __restrict__ qb,
                           const float* __restrict__ fw,  const float* __restrict__ fb,
                           const float* __restrict__ eqw, const float* __restrict__ eqb,
                           const float* __restrict__ efw, const float* __restrict__ efb,
                           float* __restrict__ qn, float* __restrict__ aq, float* __restrict__ af){
  int wid = blockIdx.x * (blockDim.x >> 6) + (threadIdx.x >> 6);
  if (wid >= ROWS) return;
  int lane = threadIdx.x & 63;
  int b = wid / NTOK, t = wid - b*NTOK;
  const float* qp = query + (size_t)wid * DIM;
  float x[6];
  #pragma unroll
  for (int j = 0; j < 6; j++) x[j] = qp[j*64 + lane];
  if (t >= L1START && t < L2START){
    const float* fp = feat + ((size_t)b*NMID + (t - L1START)) * DIM;
    #pragma unroll
    for (int j = 0; j < 6; j++) x[j] += fp[j*64 + lane];
  }
  float y[6], z[6];
  ln384(x, y, qw, qb, lane);                 // qn
  {
    float* o = qn + (size_t)wid * DIM;
    #pragma unroll
    for (int j = 0; j < 6; j++) o[j*64 + lane] = y[j];
  }
  ln384(y, z, eqw, eqb, lane);               // aq = LN(qn)
  {
    float* o = aq + (size_t)wid * DIM;
    #pragma unroll
    for (int j = 0; j < 6; j++) o[j*64 + lane] = z[j];
  }
  ln384(x, y, fw, fb, lane);                 // fn
  ln384(y, z, efw, efb, lane);               // af = LN(fn)
  {
    float* o = af + (size_t)wid * DIM;
    #pragma unroll
    for (int j = 0; j < 6; j++) o[j*64 + lane] = z[j];
  }
}

// plain LN: out = LN(in, w, b)
__global__ void k_ln(const float* __restrict__ in, const float* __restrict__ w,
                     const float* __restrict__ b, float* __restrict__ out){
  int wid = blockIdx.x * (blockDim.x >> 6) + (threadIdx.x >> 6);
  if (wid >= ROWS) return;
  int lane = threadIdx.x & 63;
  float x[6], y[6];
  const float* p = in + (size_t)wid * DIM;
  #pragma unroll
  for (int j = 0; j < 6; j++) x[j] = p[j*64 + lane];
  ln384(x, y, w, b, lane);
  float* o = out + (size_t)wid * DIM;
  #pragma unroll
  for (int j = 0; j < 6; j++) o[j*64 + lane] = y[j];
}

// C[M,N] = A[M,K] @ W[K,N] + bias (+ R).  BM=BN=64, BK=16, 256 threads, 4x4 microtile.
__global__ __launch_bounds__(256) void k_gemm(const float* __restrict__ A,
                                              const float* __restrict__ W,
                                              const float* __restrict__ bias,
                                              const float* __restrict__ R,
                                              float* __restrict__ C,
                                              int M, int N, int K){
  __shared__ float As[64][17];
  __shared__ float Ws[16][68];
  int tid = threadIdx.x;
  int tx = tid & 15, ty = tid >> 4;
  int row0 = blockIdx.y * 64, col0 = blockIdx.x * 64;
  float acc[4][4] = {};
  for (int k0 = 0; k0 < K; k0 += 16){
    #pragma unroll
    for (int u = 0; u < 4; u++){
      int idx = tid*4 + u;
      int ar = idx >> 4, ak = idx & 15;
      int gr = row0 + ar;
      As[ar][ak] = (gr < M) ? A[(size_t)gr * K + k0 + ak] : 0.f;
    }
    #pragma unroll
    for (int u = 0; u < 4; u++){
      int idx = tid*4 + u;
      int wk = idx >> 6, wc = idx & 63;
      int gc = col0 + wc;
      Ws[wk][wc] = (gc < N) ? W[(size_t)(k0 + wk) * N + gc] : 0.f;
    }
    __syncthreads();
    #pragma unroll
    for (int k = 0; k < 16; k++){
      float a4[4], b4[4];
      #pragma unroll
      for (int i = 0; i < 4; i++) a4[i] = As[ty*4 + i][k];
      #pragma unroll
      for (int j = 0; j < 4; j++) b4[j] = Ws[k][tx*4 + j];
      #pragma unroll
      for (int i = 0; i < 4; i++)
        #pragma unroll
        for (int j = 0; j < 4; j++)
          acc[i][j] += a4[i] * b4[j];
    }
    __syncthreads();
  }
  #pragma unroll
  for (int i = 0; i < 4; i++){
    int rr = row0 + ty*4 + i;
    if (rr >= M) continue;
    #pragma unroll
    for (int j = 0; j < 4; j++){
      int cc = col0 + tx*4 + j;
      if (cc >= N) continue;
      float v = acc[i][j] + (bias ? bias[cc] : 0.f) + (R ? R[(size_t)rr * N + cc] : 0.f);
      C[(size_t)rr * N + cc] = v;
    }
  }
}

// Multi-scale deformable sampling: one block per (b,token), one wave per head, lane = hd chan.
__global__ void k_msdeform(const float* __restrict__ value, const float* __restrict__ offp,
                           const float* __restrict__ awl, float* __restrict__ msout){
  int r = blockIdx.x;
  int head = threadIdx.x >> 6;
  int lane = threadIdx.x & 63;
  int b = r / NTOK, t = r - b*NTOK;
  // reference point of this token (its own level's grid center), stacked (d, x, y)
  int base, DL0, i;
  if (t < L1START){ base = 0; DL0 = 24; i = t; }
  else if (t < L2START){ base = L1START; DL0 = 12; i = t - L1START; }
  else { base = L2START; DL0 = 6; i = t - L2START; }
  (void)base;
  int hw = DL0 * DL0;
  int dd = i / hw; int rem = i - dd*hw; int yy = rem / DL0; int xx = rem - yy*DL0;
  float refd = (dd + 0.5f) / DL0;
  float refy = (yy + 0.5f) / DL0;
  float refx = (xx + 0.5f) / DL0;
  // softmax over the 12 (level,point) attention logits of this head
  const float* ap = awl + (size_t)r * 72 + head * 12;
  float e[12]; float mx = -1e30f;
  #pragma unroll
  for (int j = 0; j < 12; j++){ e[j] = ap[j]; mx = fmaxf(mx, e[j]); }
  float s = 0.f;
  #pragma unroll
  for (int j = 0; j < 12; j++){ e[j] = expf(e[j] - mx); s += e[j]; }
  float inv = 1.f / s;
  const float* op = offp + (size_t)r * 216 + head * 36;
  const int lstart[3] = {0, L1START, L2START};
  const int ldim[3]   = {24, 12, 6};
  float acc = 0.f;
  #pragma unroll
  for (int l = 0; l < 3; l++){
    int Dl = ldim[l];
    float fD = (float)Dl;
    int vbase = b * NTOK + lstart[l];
    #pragma unroll
    for (int p = 0; p < 4; p++){
      float od = op[l*12 + p*3 + 0];
      float ox = op[l*12 + p*3 + 1];
      float oy = op[l*12 + p*3 + 2];
      // loc = ref + off/norm, norm = (D, W, H) = (Dl,Dl,Dl); pixel = loc*size - 0.5
      float pd = (refd + od / fD) * fD - 0.5f;
      float px = (refx + ox / fD) * fD - 0.5f;
      float py = (refy + oy / fD) * fD - 0.5f;
      float fld = floorf(pd), flx = floorf(px), fly = floorf(py);
      float fd = pd - fld, fx = px - flx, fy = py - fly;
      int d0 = (int)fld, x0 = (int)flx, y0 = (int)fly;
      float aww = e[l*4 + p] * inv;
      #pragma unroll
      for (int cz = 0; cz < 2; cz++){
        #pragma unroll
        for (int cy = 0; cy < 2; cy++){
          #pragma unroll
          for (int cx = 0; cx < 2; cx++){
            int di = d0 + cz, yi = y0 + cy, xi = x0 + cx;
            float wgt = (cz ? fd : 1.f - fd) * (cy ? fy : 1.f - fy) * (cx ? fx : 1.f - fx) * aww;
            if (di >= 0 && di < Dl && yi >= 0 && yi < Dl && xi >= 0 && xi < Dl && wgt != 0.f){
              int vox = (di * Dl + yi) * Dl + xi;
              acc += wgt * value[(((size_t)(vbase + vox)) * HEADS + head) * HD + lane];
            }
          }
        }
      }
    }
  }
  msout[(size_t)r * DIM + head * HD + lane] = acc;
}

// depthwise 3x3x3 SAME conv per level segment + exact GELU
__global__ void k_dwconv_gelu(const float* __restrict__ h, const float* __restrict__ dww,
                              const float* __restrict__ dwb, float* __restrict__ h2){
  int gid = blockIdx.x * blockDim.x + threadIdx.x;
  if (gid >= ROWS * HID) return;
  int c = gid % HID;
  int r = gid / HID;
  int b = r / NTOK, t = r - b*NTOK;
  int base, DL;
  if (t < L1START){ base = 0; DL = 24; }
  else if (t < L2START){ base = L1START; DL = 12; }
  else { base = L2START; DL = 6; }
  int i = t - base;
  int hw = DL * DL;
  int dd = i / hw; int rem = i - dd*hw; int yy = rem / DL; int xx = rem - yy*DL;
  float acc = 0.f;
  #pragma unroll
  for (int kz = 0; kz < 3; kz++){
    int nd = dd + kz - 1; if (nd < 0 || nd >= DL) continue;
    #pragma unroll
    for (int ky = 0; ky < 3; ky++){
      int ny = yy + ky - 1; if (ny < 0 || ny >= DL) continue;
      #pragma unroll
      for (int kx = 0; kx < 3; kx++){
        int nx = xx + kx - 1; if (nx < 0 || nx >= DL) continue;
        int nt = base + (nd * DL + ny) * DL + nx;
        acc += h[((size_t)(b*NTOK + nt)) * HID + c] * dww[((kz*3 + ky)*3 + kx) * HID + c];
      }
    }
  }
  acc += dwb[c];
  float g = 0.5f * acc * (1.f + erff(acc * 0.70710678118654752440f));
  h2[(size_t)r * HID + c] = g;
}

extern "C" void kernel_launch(void* const* d_in, const int* in_sizes, int n_in,
                              void* d_out, int out_size, void* d_ws, size_t ws_size,
                              hipStream_t stream){
  const float* query = (const float*)d_in[0];
  const float* feat  = (const float*)d_in[2];
  const float* qnw = (const float*)d_in[8],  *qnb = (const float*)d_in[9];
  const float* fnw = (const float*)d_in[10], *fnb = (const float*)d_in[11];
  const float* eqw = (const float*)d_in[12], *eqb = (const float*)d_in[13];
  const float* efw = (const float*)d_in[14], *efb = (const float*)d_in[15];
  const float* ffw = (const float*)d_in[16], *ffb = (const float*)d_in[17];
  const float* off_w = (const float*)d_in[18], *off_b = (const float*)d_in[19];
  const float* aw_w  = (const float*)d_in[20], *aw_b  = (const float*)d_in[21];
  const float* val_w = (const float*)d_in[22], *val_b = (const float*)d_in[23];
  const float* out_w = (const float*)d_in[24], *out_b = (const float*)d_in[25];
  const float* fc1_w = (const float*)d_in[26], *fc1_b = (const float*)d_in[27];
  const float* dw_w  = (const float*)d_in[28], *dw_b  = (const float*)d_in[29];
  const float* fc2_w = (const float*)d_in[30], *fc2_b = (const float*)d_in[31];
  float* out = (float*)d_out;

  // workspace layout (floats), ~230 MB total with reuse
  float* ws   = (float*)d_ws;
  float* bufA = ws;                          // qn                         [ROWS,384]
  float* bufB = bufA + (size_t)ROWS * 384;   // aq  -> h                   [ROWS,384]
  float* bufC = bufB + (size_t)ROWS * 384;   // af  -> msout -> t          [ROWS,384]
  float* bufD = bufC + (size_t)ROWS * 384;   // value -> y1                [ROWS,384]
  float* bufE = bufD + (size_t)ROWS * 384;   // off -> h2                  [ROWS,216]
  float* bufF = bufE + (size_t)ROWS * 216;   // aw logits                  [ROWS,72]

  int lnBlocks = ROWS / 4;  // 4 waves (tokens) per 256-thread block; 31536 % 4 == 0

  k_ln_front<<<lnBlocks, 256, 0, stream>>>(query, feat, qnw, qnb, fnw, fnb,
                                           eqw, eqb, efw, efb, bufA, bufB, bufC);

  dim3 gv((384 + 63) / 64, (ROWS + 63) / 64);
  dim3 go((216 + 63) / 64, (ROWS + 63) / 64);
  dim3 ga((72 + 63) / 64,  (ROWS + 63) / 64);
  dim3 g1((96 + 63) / 64,  (ROWS + 63) / 64);

  // value = af @ val_w + val_b
  k_gemm<<<gv, 256, 0, stream>>>(bufC, val_w, val_b, nullptr, bufD, ROWS, 384, 384);
  // off = aq @ off_w + off_b
  k_gemm<<<go, 256, 0, stream>>>(bufB, off_w, off_b, nullptr, bufE, ROWS, 216, 384);
  // aw logits = aq @ aw_w + aw_b
  k_gemm<<<ga, 256, 0, stream>>>(bufB, aw_w, aw_b, nullptr, bufF, ROWS, 72, 384);
  // deformable sampling -> msout (bufC, af dead)
  k_msdeform<<<ROWS, 384, 0, stream>>>(bufD, bufE, bufF, bufC);
  // y1 = msout @ out_w + out_b + qn   (bufD, value dead)
  k_gemm<<<gv, 256, 0, stream>>>(bufC, out_w, out_b, bufA, bufD, ROWS, 384, 384);
  // t = LN(y1, ffn_norm)  (bufC, msout dead)
  k_ln<<<lnBlocks, 256, 0, stream>>>(bufD, ffw, ffb, bufC);
  // h = t @ fc1_w + fc1_b   (bufB, aq dead)
  k_gemm<<<g1, 256, 0, stream>>>(bufC, fc1_w, fc1_b, nullptr, bufB, ROWS, 96, 384);
  // h2 = gelu(dwconv(h))    (bufE, off dead)
  k_dwconv_gelu<<<(ROWS * HID + 255) / 256, 256, 0, stream>>>(bufB, dw_w, dw_b, bufE);
  // out = h2 @ fc2_w + fc2_b + y1
  k_gemm<<<gv, 256, 0, stream>>>(bufE, fc2_w, fc2_b, bufD, out, ROWS, 384, 96);
}

// Round 2
// 1213.235 us; speedup vs baseline: 1.3866x; 1.3866x over previous
//
#include <hip/hip_runtime.h>
#include <cstdint>
#include <cstddef>

// Problem constants (fixed by the reference file)
#define DIM    384
#define HEADS  6
#define HD     64
#define NTOK   15768
#define NMID   1728
#define BATCH  2
#define ROWS   (BATCH*NTOK)   // 31536
#define L1START 13824         // 8*NMID
#define L2START 15552         // 9*NMID
#define HID    96

__device__ __forceinline__ float wave_sum(float v){
  #pragma unroll
  for (int o = 32; o; o >>= 1) v += __shfl_xor(v, o, 64);
  return v;
}

// LayerNorm over 384 channels held as 6 regs/lane (c = j*64 + lane)
__device__ __forceinline__ void ln384(const float* x, float* y,
                                      const float* __restrict__ w,
                                      const float* __restrict__ b, int lane){
  float s = 0.f;
  #pragma unroll
  for (int j = 0; j < 6; j++) s += x[j];
  s = wave_sum(s);
  float m = s * (1.f/384.f);
  float v = 0.f;
  #pragma unroll
  for (int j = 0; j < 6; j++){ float d = x[j] - m; v += d*d; }
  v = wave_sum(v) * (1.f/384.f);
  float rs = rsqrtf(v + 1e-6f);
  #pragma unroll
  for (int j = 0; j < 6; j++){
    int c = j*64 + lane;
    y[j] = (x[j] - m) * rs * w[c] + b[c];
  }
}

// q = query (+feat on mid segment); qn=LN(q,qnorm); aq=LN(qn,ext_q); af=LN(LN(q,fnorm),ext_f)
__global__ void k_ln_front(const float* __restrict__ query, const float* __restrict__ feat,
                           const float* __restrict__ qw,  const float* __restrict__ qb,
                           const float* __restrict__ fw,  const float* __restrict__ fb,
                           const float* __restrict__ eqw, const float* __restrict__ eqb,
                           const float* __restrict__ efw, const float* __restrict__ efb,
                           float* __restrict__ qn, float* __restrict__ aq, float* __restrict__ af){
  int wid = blockIdx.x * (blockDim.x >> 6) + (threadIdx.x >> 6);
  if (wid >= ROWS) return;
  int lane = threadIdx.x & 63;
  int b = wid / NTOK, t = wid - b*NTOK;
  const float* qp = query + (size_t)wid * DIM;
  float x[6];
  #pragma unroll
  for (int j = 0; j < 6; j++) x[j] = qp[j*64 + lane];
  if (t >= L1START && t < L2START){
    const float* fp = feat + ((size_t)b*NMID + (t - L1START)) * DIM;
    #pragma unroll
    for (int j = 0; j < 6; j++) x[j] += fp[j*64 + lane];
  }
  float y[6], z[6];
  ln384(x, y, qw, qb, lane);                 // qn
  {
    float* o = qn + (size_t)wid * DIM;
    #pragma unroll
    for (int j = 0; j < 6; j++) o[j*64 + lane] = y[j];
  }
  ln384(y, z, eqw, eqb, lane);               // aq = LN(qn)
  {
    float* o = aq + (size_t)wid * DIM;
    #pragma unroll
    for (int j = 0; j < 6; j++) o[j*64 + lane] = z[j];
  }
  ln384(x, y, fw, fb, lane);                 // fn
  ln384(y, z, efw, efb, lane);               // af = LN(fn)
  {
    float* o = af + (size_t)wid * DIM;
    #pragma unroll
    for (int j = 0; j < 6; j++) o[j*64 + lane] = z[j];
  }
}

// plain LN: out = LN(in, w, b)
__global__ void k_ln(const float* __restrict__ in, const float* __restrict__ w,
                     const float* __restrict__ b, float* __restrict__ out){
  int wid = blockIdx.x * (blockDim.x >> 6) + (threadIdx.x >> 6);
  if (wid >= ROWS) return;
  int lane = threadIdx.x & 63;
  float x[6], y[6];
  const float* p = in + (size_t)wid * DIM;
  #pragma unroll
  for (int j = 0; j < 6; j++) x[j] = p[j*64 + lane];
  ln384(x, y, w, b, lane);
  float* o = out + (size_t)wid * DIM;
  #pragma unroll
  for (int j = 0; j < 6; j++) o[j*64 + lane] = y[j];
}

// C[M,N] = A[M,K] @ W[K,N] + bias (+ R).  BM=BN=64, BK=16, 256 threads, 4x4 microtile.
__global__ __launch_bounds__(256) void k_gemm(const float* __restrict__ A,
                                              const float* __restrict__ W,
                                              const float* __restrict__ bias,
                                              const float* __restrict__ R,
                                              float* __restrict__ C,
                                              int M, int N, int K){
  __shared__ float As[64][17];
  __shared__ float Ws[16][68];
  int tid = threadIdx.x;
  int tx = tid & 15, ty = tid >> 4;
  int row0 = blockIdx.y * 64, col0 = blockIdx.x * 64;
  float acc[4][4] = {};
  for (int k0 = 0; k0 < K; k0 += 16){
    #pragma unroll
    for (int u = 0; u < 4; u++){
      int idx = tid*4 + u;
      int ar = idx >> 4, ak = idx & 15;
      int gr = row0 + ar;
      As[ar][ak] = (gr < M) ? A[(size_t)gr * K + k0 + ak] : 0.f;
    }
    #pragma unroll
    for (int u = 0; u < 4; u++){
      int idx = tid*4 + u;
      int wk = idx >> 6, wc = idx & 63;
      int gc = col0 + wc;
      Ws[wk][wc] = (gc < N) ? W[(size_t)(k0 + wk) * N + gc] : 0.f;
    }
    __syncthreads();
    #pragma unroll
    for (int k = 0; k < 16; k++){
      float a4[4], b4[4];
      #pragma unroll
      for (int i = 0; i < 4; i++) a4[i] = As[ty*4 + i][k];
      #pragma unroll
      for (int j = 0; j < 4; j++) b4[j] = Ws[k][tx*4 + j];
      #pragma unroll
      for (int i = 0; i < 4; i++)
        #pragma unroll
        for (int j = 0; j < 4; j++)
          acc[i][j] += a4[i] * b4[j];
    }
    __syncthreads();
  }
  #pragma unroll
  for (int i = 0; i < 4; i++){
    int rr = row0 + ty*4 + i;
    if (rr >= M) continue;
    #pragma unroll
    for (int j = 0; j < 4; j++){
      int cc = col0 + tx*4 + j;
      if (cc >= N) continue;
      float v = acc[i][j] + (bias ? bias[cc] : 0.f) + (R ? R[(size_t)rr * N + cc] : 0.f);
      C[(size_t)rr * N + cc] = v;
    }
  }
}

// Multi-scale deformable sampling v2: one block per (b,token), one wave per head,
// lane = hd channel. Per-point setup is lane-parallel (lane j = point j, 12 active);
// the 96-corner main loop broadcasts (row, weight) via v_readlane into SGPRs so each
// corner costs ~4 VALU ops (2 readlane + load-issue + fmac) with scalar address math.
__global__ __launch_bounds__(384) void k_msdeform(const float* __restrict__ value,
                                                  const float* __restrict__ offp,
                                                  const float* __restrict__ awl,
                                                  float* __restrict__ msout){
  int r = blockIdx.x;
  int head = threadIdx.x >> 6;
  int lane = threadIdx.x & 63;
  int b = r / NTOK, t = r - b*NTOK;

  // token's own level & normalized reference point (stacked (d, x, y))
  int base, DL0;
  if (t < L1START){ base = 0; DL0 = 24; }
  else if (t < L2START){ base = L1START; DL0 = 12; }
  else { base = L2START; DL0 = 6; }
  int i = t - base;
  int hw = DL0 * DL0;
  int dd = i / hw; int rem = i - dd*hw; int yy = rem / DL0; int xx = rem - yy*DL0;
  float refd = (dd + 0.5f) / (float)DL0;
  float refy = (yy + 0.5f) / (float)DL0;
  float refx = (xx + 0.5f) / (float)DL0;

  int j = lane;  // point index handled by this lane (j < 12 active)

  // softmax over the 12 (level,point) logits of this head, lane-parallel
  float logit = -1e30f;
  if (j < 12) logit = awl[(size_t)r * 72 + head * 12 + j];
  float mx = logit;
  mx = fmaxf(mx, __shfl_xor(mx, 1));
  mx = fmaxf(mx, __shfl_xor(mx, 2));
  mx = fmaxf(mx, __shfl_xor(mx, 4));
  mx = fmaxf(mx, __shfl_xor(mx, 8));
  float e = (j < 12) ? __expf(logit - mx) : 0.f;
  float s = e;
  s += __shfl_xor(s, 1);
  s += __shfl_xor(s, 2);
  s += __shfl_xor(s, 4);
  s += __shfl_xor(s, 8);
  float aww = e / s;   // 0 for lanes >= 12

  float wk[8];
  int rowk[8];
  #pragma unroll
  for (int k = 0; k < 8; k++){ wk[k] = 0.f; rowk[k] = 0; }

  if (j < 12){
    int l = j >> 2;
    int Dl  = (l == 0) ? 24 : ((l == 1) ? 12 : 6);
    int lst = (l == 0) ? 0  : ((l == 1) ? L1START : L2START);
    const float* op = offp + (size_t)r * 216 + head * 36 + j * 3;
    float od = op[0], ox = op[1], oy = op[2];
    float fDl = (float)Dl;
    // pixel = (ref + off/norm)*size - 0.5 = ref*size + off - 0.5 (cubic grids: norm==size)
    float pd = refd * fDl + od - 0.5f;
    float px = refx * fDl + ox - 0.5f;
    float py = refy * fDl + oy - 0.5f;
    float fld = floorf(pd), flx = floorf(px), fly = floorf(py);
    float fd = pd - fld, fx = px - flx, fy = py - fly;
    int d0 = (int)fld, x0 = (int)flx, y0 = (int)fly;
    float wz[2] = {(1.f - fd) * aww, fd * aww};
    float wy[2] = {1.f - fy, fy};
    float wx[2] = {1.f - fx, fx};
    int rowbase = b * NTOK + lst;
    #pragma unroll
    for (int k = 0; k < 8; k++){
      int cz = k >> 2, cy = (k >> 1) & 1, cx = k & 1;
      int di = d0 + cz, yi = y0 + cy, xi = x0 + cx;
      bool valid = (di >= 0) & (di < Dl) & (yi >= 0) & (yi < Dl) & (xi >= 0) & (xi < Dl);
      int dc = min(max(di, 0), Dl - 1);
      int yc = min(max(yi, 0), Dl - 1);
      int xc = min(max(xi, 0), Dl - 1);
      wk[k]   = valid ? wz[cz] * wy[cy] * wx[cx] : 0.f;
      rowk[k] = rowbase + (dc * Dl + yc) * Dl + xc;
    }
  }

  // main loop: broadcast each corner's (row, weight) to SGPRs; load + fma per lane.
  unsigned h64 = (unsigned)__builtin_amdgcn_readfirstlane(head) * 64u;
  const float* vbase = value + h64;     // wave-uniform -> SGPR base
  float acc0 = 0.f, acc1 = 0.f, acc2 = 0.f, acc3 = 0.f;
  #pragma unroll
  for (int jj = 0; jj < 12; jj++){
    #pragma unroll
    for (int k = 0; k < 8; k++){
      int srow = __builtin_amdgcn_readlane(rowk[k], jj);
      float sw = __int_as_float(__builtin_amdgcn_readlane(__float_as_int(wk[k]), jj));
      float v = vbase[(size_t)((unsigned)srow * 384u) + lane];
      int slot = k & 3;
      if (slot == 0) acc0 = fmaf(sw, v, acc0);
      else if (slot == 1) acc1 = fmaf(sw, v, acc1);
      else if (slot == 2) acc2 = fmaf(sw, v, acc2);
      else acc3 = fmaf(sw, v, acc3);
    }
  }
  float acc = (acc0 + acc1) + (acc2 + acc3);
  msout[(size_t)r * DIM + h64 + lane] = acc;
}

// depthwise 3x3x3 SAME conv per level segment + exact GELU
__global__ void k_dwconv_gelu(const float* __restrict__ h, const float* __restrict__ dww,
                              const float* __restrict__ dwb, float* __restrict__ h2){
  int gid = blockIdx.x * blockDim.x + threadIdx.x;
  if (gid >= ROWS * HID) return;
  int c = gid % HID;
  int r = gid / HID;
  int b = r / NTOK, t = r - b*NTOK;
  int base, DL;
  if (t < L1START){ base = 0; DL = 24; }
  else if (t < L2START){ base = L1START; DL = 12; }
  else { base = L2START; DL = 6; }
  int i = t - base;
  int hw = DL * DL;
  int dd = i / hw; int rem = i - dd*hw; int yy = rem / DL; int xx = rem - yy*DL;
  float acc = 0.f;
  #pragma unroll
  for (int kz = 0; kz < 3; kz++){
    int nd = dd + kz - 1; if (nd < 0 || nd >= DL) continue;
    #pragma unroll
    for (int ky = 0; ky < 3; ky++){
      int ny = yy + ky - 1; if (ny < 0 || ny >= DL) continue;
      #pragma unroll
      for (int kx = 0; kx < 3; kx++){
        int nx = xx + kx - 1; if (nx < 0 || nx >= DL) continue;
        int nt = base + (nd * DL + ny) * DL + nx;
        acc += h[((size_t)(b*NTOK + nt)) * HID + c] * dww[((kz*3 + ky)*3 + kx) * HID + c];
      }
    }
  }
  acc += dwb[c];
  float g = 0.5f * acc * (1.f + erff(acc * 0.70710678118654752440f));
  h2[(size_t)r * HID + c] = g;
}

extern "C" void kernel_launch(void* const* d_in, const int* in_sizes, int n_in,
                              void* d_out, int out_size, void* d_ws, size_t ws_size,
                              hipStream_t stream){
  const float* query = (const float*)d_in[0];
  const float* feat  = (const float*)d_in[2];
  const float* qnw = (const float*)d_in[8],  *qnb = (const float*)d_in[9];
  const float* fnw = (const float*)d_in[10], *fnb = (const float*)d_in[11];
  const float* eqw = (const float*)d_in[12], *eqb = (const float*)d_in[13];
  const float* efw = (const float*)d_in[14], *efb = (const float*)d_in[15];
  const float* ffw = (const float*)d_in[16], *ffb = (const float*)d_in[17];
  const float* off_w = (const float*)d_in[18], *off_b = (const float*)d_in[19];
  const float* aw_w  = (const float*)d_in[20], *aw_b  = (const float*)d_in[21];
  const float* val_w = (const float*)d_in[22], *val_b = (const float*)d_in[23];
  const float* out_w = (const float*)d_in[24], *out_b = (const float*)d_in[25];
  const float* fc1_w = (const float*)d_in[26], *fc1_b = (const float*)d_in[27];
  const float* dw_w  = (const float*)d_in[28], *dw_b  = (const float*)d_in[29];
  const float* fc2_w = (const float*)d_in[30], *fc2_b = (const float*)d_in[31];
  float* out = (float*)d_out;

  // workspace layout (floats), ~230 MB total with reuse
  float* ws   = (float*)d_ws;
  float* bufA = ws;                          // qn                         [ROWS,384]
  float* bufB = bufA + (size_t)ROWS * 384;   // aq  -> h                   [ROWS,384]
  float* bufC = bufB + (size_t)ROWS * 384;   // af  -> msout -> t          [ROWS,384]
  float* bufD = bufC + (size_t)ROWS * 384;   // value -> y1                [ROWS,384]
  float* bufE = bufD + (size_t)ROWS * 384;   // off -> h2                  [ROWS,216]
  float* bufF = bufE + (size_t)ROWS * 216;   // aw logits                  [ROWS,72]

  int lnBlocks = ROWS / 4;  // 4 waves (tokens) per 256-thread block; 31536 % 4 == 0

  k_ln_front<<<lnBlocks, 256, 0, stream>>>(query, feat, qnw, qnb, fnw, fnb,
                                           eqw, eqb, efw, efb, bufA, bufB, bufC);

  dim3 gv((384 + 63) / 64, (ROWS + 63) / 64);
  dim3 go((216 + 63) / 64, (ROWS + 63) / 64);
  dim3 ga((72 + 63) / 64,  (ROWS + 63) / 64);
  dim3 g1((96 + 63) / 64,  (ROWS + 63) / 64);

  // value = af @ val_w + val_b
  k_gemm<<<gv, 256, 0, stream>>>(bufC, val_w, val_b, nullptr, bufD, ROWS, 384, 384);
  // off = aq @ off_w + off_b
  k_gemm<<<go, 256, 0, stream>>>(bufB, off_w, off_b, nullptr, bufE, ROWS, 216, 384);
  // aw logits = aq @ aw_w + aw_b
  k_gemm<<<ga, 256, 0, stream>>>(bufB, aw_w, aw_b, nullptr, bufF, ROWS, 72, 384);
  // deformable sampling -> msout (bufC, af dead)
  k_msdeform<<<ROWS, 384, 0, stream>>>(bufD, bufE, bufF, bufC);
  // y1 = msout @ out_w + out_b + qn   (bufD, value dead)
  k_gemm<<<gv, 256, 0, stream>>>(bufC, out_w, out_b, bufA, bufD, ROWS, 384, 384);
  // t = LN(y1, ffn_norm)  (bufC, msout dead)
  k_ln<<<lnBlocks, 256, 0, stream>>>(bufD, ffw, ffb, bufC);
  // h = t @ fc1_w + fc1_b   (bufB, aq dead)
  k_gemm<<<g1, 256, 0, stream>>>(bufC, fc1_w, fc1_b, nullptr, bufB, ROWS, 96, 384);
  // h2 = gelu(dwconv(h))    (bufE, off dead)
  k_dwconv_gelu<<<(ROWS * HID + 255) / 256, 256, 0, stream>>>(bufB, dw_w, dw_b, bufE);
  // out = h2 @ fc2_w + fc2_b + y1
  k_gemm<<<gv, 256, 0, stream>>>(bufE, fc2_w, fc2_b, bufD, out, ROWS, 384, 96);
}

// Round 3
// 753.521 us; speedup vs baseline: 2.2325x; 1.6101x over previous
//
#include <hip/hip_runtime.h>
#include <cstdint>
#include <cstddef>

// Problem constants (fixed by the reference file)
#define DIM    384
#define HEADS  6
#define HD     64
#define NTOK   15768
#define NMID   1728
#define BATCH  2
#define ROWS   (BATCH*NTOK)   // 31536
#define MPAD   31616          // 247*128  (GEMM row-tile padding)
#define L1START 13824         // 8*NMID
#define L2START 15552         // 9*NMID
#define HID    96

typedef __attribute__((ext_vector_type(8))) short short8;   // 8 bf16 (4 VGPRs)
typedef __attribute__((ext_vector_type(4))) float floatx4;  // MFMA accumulator

__device__ __forceinline__ unsigned short f2bf(float x){
  unsigned u = __float_as_uint(x);
  unsigned r = (u + 0x7FFFu + ((u >> 16) & 1u)) >> 16;   // round-to-nearest-even
  return (unsigned short)r;
}

__device__ __forceinline__ float wave_sum(float v){
  #pragma unroll
  for (int o = 32; o; o >>= 1) v += __shfl_xor(v, o, 64);
  return v;
}

// LayerNorm over 384 channels held as 6 regs/lane (c = j*64 + lane)
__device__ __forceinline__ void ln384(const float* x, float* y,
                                      const float* __restrict__ w,
                                      const float* __restrict__ b, int lane){
  float s = 0.f;
  #pragma unroll
  for (int j = 0; j < 6; j++) s += x[j];
  s = wave_sum(s);
  float m = s * (1.f/384.f);
  float v = 0.f;
  #pragma unroll
  for (int j = 0; j < 6; j++){ float d = x[j] - m; v += d*d; }
  v = wave_sum(v) * (1.f/384.f);
  float rs = rsqrtf(v + 1e-6f);
  #pragma unroll
  for (int j = 0; j < 6; j++){
    int c = j*64 + lane;
    y[j] = (x[j] - m) * rs * w[c] + b[c];
  }
}

// q = query (+feat on mid segment); qn=LN(q) fp32; aq=LN(qn) bf16; af=LN(LN(q,fnorm)) bf16
__global__ void k_ln_front(const float* __restrict__ query, const float* __restrict__ feat,
                           const float* __restrict__ qw,  const float* __restrict__ qb,
                           const float* __restrict__ fw,  const float* __restrict__ fb,
                           const float* __restrict__ eqw, const float* __restrict__ eqb,
                           const float* __restrict__ efw, const float* __restrict__ efb,
                           float* __restrict__ qn, unsigned short* __restrict__ aq,
                           unsigned short* __restrict__ af){
  int wid = blockIdx.x * (blockDim.x >> 6) + (threadIdx.x >> 6);
  if (wid >= ROWS) return;
  int lane = threadIdx.x & 63;
  int b = wid / NTOK, t = wid - b*NTOK;
  const float* qp = query + (size_t)wid * DIM;
  float x[6];
  #pragma unroll
  for (int j = 0; j < 6; j++) x[j] = qp[j*64 + lane];
  if (t >= L1START && t < L2START){
    const float* fp = feat + ((size_t)b*NMID + (t - L1START)) * DIM;
    #pragma unroll
    for (int j = 0; j < 6; j++) x[j] += fp[j*64 + lane];
  }
  float y[6], z[6];
  ln384(x, y, qw, qb, lane);                 // qn
  {
    float* o = qn + (size_t)wid * DIM;
    #pragma unroll
    for (int j = 0; j < 6; j++) o[j*64 + lane] = y[j];
  }
  ln384(y, z, eqw, eqb, lane);               // aq = LN(qn)
  {
    unsigned short* o = aq + (size_t)wid * DIM;
    #pragma unroll
    for (int j = 0; j < 6; j++) o[j*64 + lane] = f2bf(z[j]);
  }
  ln384(x, y, fw, fb, lane);                 // fn
  ln384(y, z, efw, efb, lane);               // af = LN(fn)
  {
    unsigned short* o = af + (size_t)wid * DIM;
    #pragma unroll
    for (int j = 0; j < 6; j++) o[j*64 + lane] = f2bf(z[j]);
  }
}

// plain LN: out_bf16 = LN(in_f32, w, b)
__global__ void k_ln(const float* __restrict__ in, const float* __restrict__ w,
                     const float* __restrict__ b, unsigned short* __restrict__ out){
  int wid = blockIdx.x * (blockDim.x >> 6) + (threadIdx.x >> 6);
  if (wid >= ROWS) return;
  int lane = threadIdx.x & 63;
  float x[6], y[6];
  const float* p = in + (size_t)wid * DIM;
  #pragma unroll
  for (int j = 0; j < 6; j++) x[j] = p[j*64 + lane];
  ln384(x, y, w, b, lane);
  unsigned short* o = out + (size_t)wid * DIM;
  #pragma unroll
  for (int j = 0; j < 6; j++) o[j*64 + lane] = f2bf(y[j]);
}

// weight convert + transpose: Wt[n*K + k] = bf16(W[k*N + n]); zero-pad n in [N, Npad)
__global__ void k_cvt_w(const float* __restrict__ W, unsigned short* __restrict__ Wt,
                        int K, int N, int Npad){
  int id = blockIdx.x * blockDim.x + threadIdx.x;
  if (id >= Npad * K) return;
  int n = id / K, k = id - n * K;
  float v = (n < N) ? W[(size_t)k * N + n] : 0.f;
  Wt[id] = f2bf(v);
}

// bf16 MFMA GEMM: C[M,N] = A[Mpad,K]bf16 @ Wt[Npad,K]bf16^T + bias (+R).
// 128x128 tile, BK=32, 256 threads (4 waves, each a 64x64 quadrant of 16 MFMAs).
// Staging via global_load_lds width=16 (wave-uniform LDS base + lane*16).
__global__ __launch_bounds__(256) void k_gemm_bf16(
    const unsigned short* __restrict__ A,
    const unsigned short* __restrict__ Wt,
    const float* __restrict__ bias,
    const float* __restrict__ R,
    float* __restrict__ C,
    int M, int N, int K){
  __shared__ __align__(16) unsigned short As[128*32];
  __shared__ __align__(16) unsigned short Bs[128*32];
  int tid = threadIdx.x;
  int w = tid >> 6, lane = tid & 63;
  int m0 = blockIdx.y * 128, n0 = blockIdx.x * 128;
  int m_off = (w & 1) * 64, n_off = (w >> 1) * 64;

  floatx4 acc[4][4] = {};

  int sr = lane >> 2;          // row within 16-row staging chunk
  int sc = (lane & 3) * 8;     // bf16-element offset within row (16B granules)
  int lrow = lane & 15;        // MFMA row/col within 16
  int kq = (lane >> 4) * 8;    // k-offset of this lane's 8-element fragment

  for (int k0 = 0; k0 < K; k0 += 32){
    #pragma unroll
    for (int s = 0; s < 2; s++){
      int c = w * 2 + s;       // chunk 0..7 (16 rows each)
      const unsigned short* ga = A  + (size_t)(m0 + c*16 + sr) * K + k0 + sc;
      __builtin_amdgcn_global_load_lds(
          (const __attribute__((address_space(1))) void*)ga,
          (__attribute__((address_space(3))) void*)(As + c*512), 16, 0, 0);
      const unsigned short* gb = Wt + (size_t)(n0 + c*16 + sr) * K + k0 + sc;
      __builtin_amdgcn_global_load_lds(
          (const __attribute__((address_space(1))) void*)gb,
          (__attribute__((address_space(3))) void*)(Bs + c*512), 16, 0, 0);
    }
    __syncthreads();
    short8 afr[4], bfr[4];
    #pragma unroll
    for (int i = 0; i < 4; i++)
      afr[i] = *(const short8*)(As + (m_off + i*16 + lrow)*32 + kq);
    #pragma unroll
    for (int j = 0; j < 4; j++)
      bfr[j] = *(const short8*)(Bs + (n_off + j*16 + lrow)*32 + kq);
    #pragma unroll
    for (int i = 0; i < 4; i++)
      #pragma unroll
      for (int j = 0; j < 4; j++)
        acc[i][j] = __builtin_amdgcn_mfma_f32_16x16x32_bf16(afr[i], bfr[j], acc[i][j], 0, 0, 0);
    __syncthreads();
  }

  // epilogue: C/D layout col = lane&15, row = (lane>>4)*4 + reg
  int cn = n0 + n_off + lrow;
  int rbase = m0 + m_off + (lane >> 4) * 4;
  #pragma unroll
  for (int j = 0; j < 4; j++){
    int n = cn + j*16;
    if (n >= N) continue;
    float bj = bias[n];
    #pragma unroll
    for (int i = 0; i < 4; i++){
      int mb = rbase + i*16;
      #pragma unroll
      for (int r = 0; r < 4; r++){
        int m = mb + r;
        if (m < M){
          float v = acc[i][j][r] + bj;
          if (R) v += R[(size_t)m * N + n];
          C[(size_t)m * N + n] = v;
        }
      }
    }
  }
}

// Multi-scale deformable sampling: one block per (b,token), one wave per head,
// lane = hd channel. Per-point setup lane-parallel; 96-corner loop broadcasts
// (row, weight) via v_readlane to SGPRs. Output written as bf16 (feeds out-GEMM).
__global__ __launch_bounds__(384) void k_msdeform(const float* __restrict__ value,
                                                  const float* __restrict__ offp,
                                                  const float* __restrict__ awl,
                                                  unsigned short* __restrict__ msout){
  int r = blockIdx.x;
  int head = threadIdx.x >> 6;
  int lane = threadIdx.x & 63;
  int b = r / NTOK, t = r - b*NTOK;

  int base, DL0;
  if (t < L1START){ base = 0; DL0 = 24; }
  else if (t < L2START){ base = L1START; DL0 = 12; }
  else { base = L2START; DL0 = 6; }
  int i = t - base;
  int hw = DL0 * DL0;
  int dd = i / hw; int rem = i - dd*hw; int yy = rem / DL0; int xx = rem - yy*DL0;
  float refd = (dd + 0.5f) / (float)DL0;
  float refy = (yy + 0.5f) / (float)DL0;
  float refx = (xx + 0.5f) / (float)DL0;

  int j = lane;  // point index (j < 12 active)

  float logit = -1e30f;
  if (j < 12) logit = awl[(size_t)r * 72 + head * 12 + j];
  float mx = logit;
  mx = fmaxf(mx, __shfl_xor(mx, 1));
  mx = fmaxf(mx, __shfl_xor(mx, 2));
  mx = fmaxf(mx, __shfl_xor(mx, 4));
  mx = fmaxf(mx, __shfl_xor(mx, 8));
  float e = (j < 12) ? __expf(logit - mx) : 0.f;
  float s = e;
  s += __shfl_xor(s, 1);
  s += __shfl_xor(s, 2);
  s += __shfl_xor(s, 4);
  s += __shfl_xor(s, 8);
  float aww = e / s;

  float wk[8];
  int rowk[8];
  #pragma unroll
  for (int k = 0; k < 8; k++){ wk[k] = 0.f; rowk[k] = 0; }

  if (j < 12){
    int l = j >> 2;
    int Dl  = (l == 0) ? 24 : ((l == 1) ? 12 : 6);
    int lst = (l == 0) ? 0  : ((l == 1) ? L1START : L2START);
    const float* op = offp + (size_t)r * 216 + head * 36 + j * 3;
    float od = op[0], ox = op[1], oy = op[2];
    float fDl = (float)Dl;
    float pd = refd * fDl + od - 0.5f;
    float px = refx * fDl + ox - 0.5f;
    float py = refy * fDl + oy - 0.5f;
    float fld = floorf(pd), flx = floorf(px), fly = floorf(py);
    float fd = pd - fld, fx = px - flx, fy = py - fly;
    int d0 = (int)fld, x0 = (int)flx, y0 = (int)fly;
    float wz[2] = {(1.f - fd) * aww, fd * aww};
    float wy[2] = {1.f - fy, fy};
    float wx[2] = {1.f - fx, fx};
    int rowbase = b * NTOK + lst;
    #pragma unroll
    for (int k = 0; k < 8; k++){
      int cz = k >> 2, cy = (k >> 1) & 1, cx = k & 1;
      int di = d0 + cz, yi = y0 + cy, xi = x0 + cx;
      bool valid = (di >= 0) & (di < Dl) & (yi >= 0) & (yi < Dl) & (xi >= 0) & (xi < Dl);
      int dc = min(max(di, 0), Dl - 1);
      int yc = min(max(yi, 0), Dl - 1);
      int xc = min(max(xi, 0), Dl - 1);
      wk[k]   = valid ? wz[cz] * wy[cy] * wx[cx] : 0.f;
      rowk[k] = rowbase + (dc * Dl + yc) * Dl + xc;
    }
  }

  unsigned h64 = (unsigned)__builtin_amdgcn_readfirstlane(head) * 64u;
  const float* vbase = value + h64;
  float acc0 = 0.f, acc1 = 0.f, acc2 = 0.f, acc3 = 0.f;
  #pragma unroll
  for (int jj = 0; jj < 12; jj++){
    #pragma unroll
    for (int k = 0; k < 8; k++){
      int srow = __builtin_amdgcn_readlane(rowk[k], jj);
      float sw = __int_as_float(__builtin_amdgcn_readlane(__float_as_int(wk[k]), jj));
      float v = vbase[(size_t)((unsigned)srow * 384u) + lane];
      int slot = k & 3;
      if (slot == 0) acc0 = fmaf(sw, v, acc0);
      else if (slot == 1) acc1 = fmaf(sw, v, acc1);
      else if (slot == 2) acc2 = fmaf(sw, v, acc2);
      else acc3 = fmaf(sw, v, acc3);
    }
  }
  float acc = (acc0 + acc1) + (acc2 + acc3);
  msout[(size_t)r * DIM + h64 + lane] = f2bf(acc);
}

// depthwise 3x3x3 SAME conv per level segment + exact GELU; bf16 output (feeds fc2 GEMM)
__global__ void k_dwconv_gelu(const float* __restrict__ h, const float* __restrict__ dww,
                              const float* __restrict__ dwb, unsigned short* __restrict__ h2){
  int gid = blockIdx.x * blockDim.x + threadIdx.x;
  if (gid >= ROWS * HID) return;
  int c = gid % HID;
  int r = gid / HID;
  int b = r / NTOK, t = r - b*NTOK;
  int base, DL;
  if (t < L1START){ base = 0; DL = 24; }
  else if (t < L2START){ base = L1START; DL = 12; }
  else { base = L2START; DL = 6; }
  int i = t - base;
  int hw = DL * DL;
  int dd = i / hw; int rem = i - dd*hw; int yy = rem / DL; int xx = rem - yy*DL;
  float acc = 0.f;
  #pragma unroll
  for (int kz = 0; kz < 3; kz++){
    int nd = dd + kz - 1; if (nd < 0 || nd >= DL) continue;
    #pragma unroll
    for (int ky = 0; ky < 3; ky++){
      int ny = yy + ky - 1; if (ny < 0 || ny >= DL) continue;
      #pragma unroll
      for (int kx = 0; kx < 3; kx++){
        int nx = xx + kx - 1; if (nx < 0 || nx >= DL) continue;
        int nt = base + (nd * DL + ny) * DL + nx;
        acc += h[((size_t)(b*NTOK + nt)) * HID + c] * dww[((kz*3 + ky)*3 + kx) * HID + c];
      }
    }
  }
  acc += dwb[c];
  float g = 0.5f * acc * (1.f + erff(acc * 0.70710678118654752440f));
  h2[(size_t)r * HID + c] = f2bf(g);
}

extern "C" void kernel_launch(void* const* d_in, const int* in_sizes, int n_in,
                              void* d_out, int out_size, void* d_ws, size_t ws_size,
                              hipStream_t stream){
  const float* query = (const float*)d_in[0];
  const float* feat  = (const float*)d_in[2];
  const float* qnw = (const float*)d_in[8],  *qnb = (const float*)d_in[9];
  const float* fnw = (const float*)d_in[10], *fnb = (const float*)d_in[11];
  const float* eqw = (const float*)d_in[12], *eqb = (const float*)d_in[13];
  const float* efw = (const float*)d_in[14], *efb = (const float*)d_in[15];
  const float* ffw = (const float*)d_in[16], *ffb = (const float*)d_in[17];
  const float* off_w = (const float*)d_in[18], *off_b = (const float*)d_in[19];
  const float* aw_w  = (const float*)d_in[20], *aw_b  = (const float*)d_in[21];
  const float* val_w = (const float*)d_in[22], *val_b = (const float*)d_in[23];
  const float* out_w = (const float*)d_in[24], *out_b = (const float*)d_in[25];
  const float* fc1_w = (const float*)d_in[26], *fc1_b = (const float*)d_in[27];
  const float* dw_w  = (const float*)d_in[28], *dw_b  = (const float*)d_in[29];
  const float* fc2_w = (const float*)d_in[30], *fc2_b = (const float*)d_in[31];
  float* out = (float*)d_out;

  // workspace layout (bytes), ~183 MB with aggressive reuse
  char* p = (char*)d_ws;
  float* qn            = (float*)p;          p += (size_t)ROWS*384*4;  // qn (residual)
  unsigned short* aq   = (unsigned short*)p; p += (size_t)MPAD*384*2;  // aq  -> t
  unsigned short* af   = (unsigned short*)p; p += (size_t)MPAD*384*2;  // af  -> msout
  float* value         = (float*)p;          p += (size_t)ROWS*384*4;  // value -> y1
  float* offb          = (float*)p;          p += (size_t)ROWS*216*4;  // off   -> h
  float* awlb          = (float*)p;          p += (size_t)ROWS*72*4;   // awl   -> h2
  unsigned short* wt_val = (unsigned short*)p; p += (size_t)384*384*2;
  unsigned short* wt_off = (unsigned short*)p; p += (size_t)256*384*2;
  unsigned short* wt_aw  = (unsigned short*)p; p += (size_t)128*384*2;
  unsigned short* wt_out = (unsigned short*)p; p += (size_t)384*384*2;
  unsigned short* wt_fc1 = (unsigned short*)p; p += (size_t)128*384*2;
  unsigned short* wt_fc2 = (unsigned short*)p; p += (size_t)384*96*2;
  // aliases (lifetime-disjoint reuse)
  unsigned short* t_buf  = aq;                    // MPAD*384 bf16
  unsigned short* msout  = af;                    // MPAD*384 bf16
  float* y1              = value;                 // ROWS*384 f32
  float* h_buf           = offb;                  // ROWS*96 f32
  unsigned short* h2_buf = (unsigned short*)awlb; // MPAD*96 bf16

  // weight convert+transpose (tiny)
  k_cvt_w<<<(384*384 + 255)/256, 256, 0, stream>>>(val_w, wt_val, 384, 384, 384);
  k_cvt_w<<<(256*384 + 255)/256, 256, 0, stream>>>(off_w, wt_off, 384, 216, 256);
  k_cvt_w<<<(128*384 + 255)/256, 256, 0, stream>>>(aw_w,  wt_aw,  384, 72, 128);
  k_cvt_w<<<(384*384 + 255)/256, 256, 0, stream>>>(out_w, wt_out, 384, 384, 384);
  k_cvt_w<<<(128*384 + 255)/256, 256, 0, stream>>>(fc1_w, wt_fc1, 384, 96, 128);
  k_cvt_w<<<(384*96  + 255)/256, 256, 0, stream>>>(fc2_w, wt_fc2, 96, 384, 384);

  int lnBlocks = ROWS / 4;
  k_ln_front<<<lnBlocks, 256, 0, stream>>>(query, feat, qnw, qnb, fnw, fnb,
                                           eqw, eqb, efw, efb, qn, aq, af);

  dim3 gN384(3, MPAD/128), gN256(2, MPAD/128), gN128(1, MPAD/128);

  // value = af @ val_w + val_b
  k_gemm_bf16<<<gN384, 256, 0, stream>>>(af, wt_val, val_b, nullptr, value, ROWS, 384, 384);
  // off = aq @ off_w + off_b
  k_gemm_bf16<<<gN256, 256, 0, stream>>>(aq, wt_off, off_b, nullptr, offb, ROWS, 216, 384);
  // aw logits = aq @ aw_w + aw_b
  k_gemm_bf16<<<gN128, 256, 0, stream>>>(aq, wt_aw, aw_b, nullptr, awlb, ROWS, 72, 384);
  // deformable sampling -> msout (bf16; af dead)
  k_msdeform<<<ROWS, 384, 0, stream>>>(value, offb, awlb, msout);
  // y1 = msout @ out_w + out_b + qn   (value dead)
  k_gemm_bf16<<<gN384, 256, 0, stream>>>(msout, wt_out, out_b, qn, y1, ROWS, 384, 384);
  // t = LN(y1, ffn_norm)  (aq dead)
  k_ln<<<lnBlocks, 256, 0, stream>>>(y1, ffw, ffb, t_buf);
  // h = t @ fc1_w + fc1_b   (off dead)
  k_gemm_bf16<<<gN128, 256, 0, stream>>>(t_buf, wt_fc1, fc1_b, nullptr, h_buf, ROWS, 96, 384);
  // h2 = gelu(dwconv(h))    (awl dead)
  k_dwconv_gelu<<<(ROWS * HID + 255)/256, 256, 0, stream>>>(h_buf, dw_w, dw_b, h2_buf);
  // out = h2 @ fc2_w + fc2_b + y1
  k_gemm_bf16<<<gN384, 256, 0, stream>>>(h2_buf, wt_fc2, fc2_b, y1, out, ROWS, 384, 96);
}

// Round 4
// 640.385 us; speedup vs baseline: 2.6270x; 1.1767x over previous
//
#include <hip/hip_runtime.h>
#include <cstdint>
#include <cstddef>

// Problem constants (fixed by the reference file)
#define DIM    384
#define HEADS  6
#define HD     64
#define NTOK   15768
#define NMID   1728
#define BATCH  2
#define ROWS   (BATCH*NTOK)   // 31536
#define MPAD   31616          // 247*128  (GEMM row-tile padding)
#define L1START 13824         // 8*NMID
#define L2START 15552         // 9*NMID
#define HID    96

typedef __attribute__((ext_vector_type(8))) short short8;   // 8 bf16 (4 VGPRs)
typedef __attribute__((ext_vector_type(4))) float floatx4;  // MFMA accumulator

__device__ __forceinline__ unsigned short f2bf(float x){
  unsigned u = __float_as_uint(x);
  unsigned r = (u + 0x7FFFu + ((u >> 16) & 1u)) >> 16;   // round-to-nearest-even
  return (unsigned short)r;
}

__device__ __forceinline__ float wave_sum(float v){
  #pragma unroll
  for (int o = 32; o; o >>= 1) v += __shfl_xor(v, o, 64);
  return v;
}

// LayerNorm over 384 channels held as 6 regs/lane (c = j*64 + lane)
__device__ __forceinline__ void ln384(const float* x, float* y,
                                      const float* __restrict__ w,
                                      const float* __restrict__ b, int lane){
  float s = 0.f;
  #pragma unroll
  for (int j = 0; j < 6; j++) s += x[j];
  s = wave_sum(s);
  float m = s * (1.f/384.f);
  float v = 0.f;
  #pragma unroll
  for (int j = 0; j < 6; j++){ float d = x[j] - m; v += d*d; }
  v = wave_sum(v) * (1.f/384.f);
  float rs = rsqrtf(v + 1e-6f);
  #pragma unroll
  for (int j = 0; j < 6; j++){
    int c = j*64 + lane;
    y[j] = (x[j] - m) * rs * w[c] + b[c];
  }
}

// q = query (+feat on mid segment); qn=LN(q) fp32; aq=LN(qn) bf16; af=LN(LN(q,fnorm)) bf16
__global__ void k_ln_front(const float* __restrict__ query, const float* __restrict__ feat,
                           const float* __restrict__ qw,  const float* __restrict__ qb,
                           const float* __restrict__ fw,  const float* __restrict__ fb,
                           const float* __restrict__ eqw, const float* __restrict__ eqb,
                           const float* __restrict__ efw, const float* __restrict__ efb,
                           float* __restrict__ qn, unsigned short* __restrict__ aq,
                           unsigned short* __restrict__ af){
  int wid = blockIdx.x * (blockDim.x >> 6) + (threadIdx.x >> 6);
  if (wid >= ROWS) return;
  int lane = threadIdx.x & 63;
  int b = wid / NTOK, t = wid - b*NTOK;
  const float* qp = query + (size_t)wid * DIM;
  float x[6];
  #pragma unroll
  for (int j = 0; j < 6; j++) x[j] = qp[j*64 + lane];
  if (t >= L1START && t < L2START){
    const float* fp = feat + ((size_t)b*NMID + (t - L1START)) * DIM;
    #pragma unroll
    for (int j = 0; j < 6; j++) x[j] += fp[j*64 + lane];
  }
  float y[6], z[6];
  ln384(x, y, qw, qb, lane);                 // qn
  {
    float* o = qn + (size_t)wid * DIM;
    #pragma unroll
    for (int j = 0; j < 6; j++) o[j*64 + lane] = y[j];
  }
  ln384(y, z, eqw, eqb, lane);               // aq = LN(qn)
  {
    unsigned short* o = aq + (size_t)wid * DIM;
    #pragma unroll
    for (int j = 0; j < 6; j++) o[j*64 + lane] = f2bf(z[j]);
  }
  ln384(x, y, fw, fb, lane);                 // fn
  ln384(y, z, efw, efb, lane);               // af = LN(fn)
  {
    unsigned short* o = af + (size_t)wid * DIM;
    #pragma unroll
    for (int j = 0; j < 6; j++) o[j*64 + lane] = f2bf(z[j]);
  }
}

// plain LN: out_bf16 = LN(in_f32, w, b)
__global__ void k_ln(const float* __restrict__ in, const float* __restrict__ w,
                     const float* __restrict__ b, unsigned short* __restrict__ out){
  int wid = blockIdx.x * (blockDim.x >> 6) + (threadIdx.x >> 6);
  if (wid >= ROWS) return;
  int lane = threadIdx.x & 63;
  float x[6], y[6];
  const float* p = in + (size_t)wid * DIM;
  #pragma unroll
  for (int j = 0; j < 6; j++) x[j] = p[j*64 + lane];
  ln384(x, y, w, b, lane);
  unsigned short* o = out + (size_t)wid * DIM;
  #pragma unroll
  for (int j = 0; j < 6; j++) o[j*64 + lane] = f2bf(y[j]);
}

// One-shot weight convert+transpose for all GEMMs + combined off/aw bias.
// Wt layouts are [n*K + k] bf16, zero-padded to Npad. Segment boundaries in elements.
__global__ void k_cvt_all(const float* __restrict__ val_w, const float* __restrict__ off_w,
                          const float* __restrict__ aw_w,  const float* __restrict__ out_w,
                          const float* __restrict__ fc1_w, const float* __restrict__ fc2_w,
                          const float* __restrict__ off_b, const float* __restrict__ aw_b,
                          unsigned short* __restrict__ wt_val, unsigned short* __restrict__ wt_offaw,
                          unsigned short* __restrict__ wt_out, unsigned short* __restrict__ wt_fc1,
                          unsigned short* __restrict__ wt_fc2, float* __restrict__ offaw_b){
  int id = blockIdx.x * blockDim.x + threadIdx.x;
  if (id < 147456){                                   // val: K=384, Npad=384
    int n = id / 384, k = id - n*384;
    wt_val[id] = f2bf(val_w[(size_t)k*384 + n]);
  } else if (id < 294912){                            // off(216)+aw(72@256): K=384, Npad=384
    int i = id - 147456;
    int n = i / 384, k = i - n*384;
    float v = 0.f;
    if (n < 216) v = off_w[(size_t)k*216 + n];
    else if (n >= 256 && n < 328) v = aw_w[(size_t)k*72 + (n-256)];
    wt_offaw[i] = f2bf(v);
  } else if (id < 442368){                            // out: K=384, Npad=384
    int i = id - 294912;
    int n = i / 384, k = i - n*384;
    wt_out[i] = f2bf(out_w[(size_t)k*384 + n]);
  } else if (id < 491520){                            // fc1: K=384, N=96, Npad=128
    int i = id - 442368;
    int n = i / 384, k = i - n*384;
    wt_fc1[i] = f2bf((n < 96) ? fc1_w[(size_t)k*96 + n] : 0.f);
  } else if (id < 528384){                            // fc2: K=96, Npad=384
    int i = id - 491520;
    int n = i / 96, k = i - n*96;
    wt_fc2[i] = f2bf(fc2_w[(size_t)k*384 + n]);
  } else if (id < 528768){                            // combined off/aw bias [384]
    int n = id - 528384;
    float v = 0.f;
    if (n < 216) v = off_b[n];
    else if (n >= 256 && n < 328) v = aw_b[n-256];
    offaw_b[n] = v;
  }
}

// bf16 MFMA GEMM: C[M,N] = A[Mpad,K]bf16 @ Wt[Npad,K]bf16^T + bias (+R).
// 128x128 tile, BK=32, 256 threads. Staging via global_load_lds width=16.
template<bool BF16OUT>
__global__ __launch_bounds__(256) void k_gemm(
    const unsigned short* __restrict__ A,
    const unsigned short* __restrict__ Wt,
    const float* __restrict__ bias,
    const float* __restrict__ R,
    void* __restrict__ Cv,
    int M, int N, int K){
  __shared__ __align__(16) unsigned short As[128*32];
  __shared__ __align__(16) unsigned short Bs[128*32];
  int tid = threadIdx.x;
  int w = tid >> 6, lane = tid & 63;
  int m0 = blockIdx.y * 128, n0 = blockIdx.x * 128;
  int m_off = (w & 1) * 64, n_off = (w >> 1) * 64;

  floatx4 acc[4][4] = {};

  int sr = lane >> 2;          // row within 16-row staging chunk
  int sc = (lane & 3) * 8;     // bf16-element offset within row (16B granules)
  int lrow = lane & 15;        // MFMA row/col within 16
  int kq = (lane >> 4) * 8;    // k-offset of this lane's 8-element fragment

  for (int k0 = 0; k0 < K; k0 += 32){
    #pragma unroll
    for (int s = 0; s < 2; s++){
      int c = w * 2 + s;       // chunk 0..7 (16 rows each)
      const unsigned short* ga = A  + (size_t)(m0 + c*16 + sr) * K + k0 + sc;
      __builtin_amdgcn_global_load_lds(
          (const __attribute__((address_space(1))) void*)ga,
          (__attribute__((address_space(3))) void*)(As + c*512), 16, 0, 0);
      const unsigned short* gb = Wt + (size_t)(n0 + c*16 + sr) * K + k0 + sc;
      __builtin_amdgcn_global_load_lds(
          (const __attribute__((address_space(1))) void*)gb,
          (__attribute__((address_space(3))) void*)(Bs + c*512), 16, 0, 0);
    }
    __syncthreads();
    short8 afr[4], bfr[4];
    #pragma unroll
    for (int i = 0; i < 4; i++)
      afr[i] = *(const short8*)(As + (m_off + i*16 + lrow)*32 + kq);
    #pragma unroll
    for (int j = 0; j < 4; j++)
      bfr[j] = *(const short8*)(Bs + (n_off + j*16 + lrow)*32 + kq);
    #pragma unroll
    for (int i = 0; i < 4; i++)
      #pragma unroll
      for (int j = 0; j < 4; j++)
        acc[i][j] = __builtin_amdgcn_mfma_f32_16x16x32_bf16(afr[i], bfr[j], acc[i][j], 0, 0, 0);
    __syncthreads();
  }

  // epilogue: C/D layout col = lane&15, row = (lane>>4)*4 + reg
  int cn = n0 + n_off + lrow;
  int rbase = m0 + m_off + (lane >> 4) * 4;
  #pragma unroll
  for (int j = 0; j < 4; j++){
    int n = cn + j*16;
    if (n >= N) continue;
    float bj = bias[n];
    #pragma unroll
    for (int i = 0; i < 4; i++){
      int mb = rbase + i*16;
      #pragma unroll
      for (int r = 0; r < 4; r++){
        int m = mb + r;
        if (m < M){
          float v = acc[i][j][r] + bj;
          if (R) v += R[(size_t)m * N + n];
          if (BF16OUT) ((unsigned short*)Cv)[(size_t)m * N + n] = f2bf(v);
          else         ((float*)Cv)[(size_t)m * N + n] = v;
        }
      }
    }
  }
}

// Multi-scale deformable sampling: one block per (b,token) [XCD-swizzled], one wave per
// head, lane = hd channel. Setup lane-parallel (lane j = point j); 96-corner loop
// broadcasts packed (bf16 weight << 16 | row) via one readlane per corner; value is bf16.
__global__ __launch_bounds__(384) void k_msdeform(const unsigned short* __restrict__ value,
                                                  const float* __restrict__ offaw,
                                                  unsigned short* __restrict__ msout){
  int bx = blockIdx.x;
  // XCD-aware swizzle: consecutive tokens on the same XCD (8 XCDs, round-robin dispatch)
  int r = (bx & 7) * (ROWS/8) + (bx >> 3);
  int head = threadIdx.x >> 6;
  int lane = threadIdx.x & 63;
  int b = r / NTOK, t = r - b*NTOK;

  int base, DL0;
  if (t < L1START){ base = 0; DL0 = 24; }
  else if (t < L2START){ base = L1START; DL0 = 12; }
  else { base = L2START; DL0 = 6; }
  int i = t - base;
  int hw = DL0 * DL0;
  int dd = i / hw; int rem = i - dd*hw; int yy = rem / DL0; int xx = rem - yy*DL0;
  float refd = (dd + 0.5f) / (float)DL0;
  float refy = (yy + 0.5f) / (float)DL0;
  float refx = (xx + 0.5f) / (float)DL0;

  int j = lane;  // point index (j < 12 active)

  float logit = (j < 12) ? offaw[(size_t)r * 384 + 256 + head * 12 + j] : -1e30f;
  float mx = logit;
  mx = fmaxf(mx, __shfl_xor(mx, 1));
  mx = fmaxf(mx, __shfl_xor(mx, 2));
  mx = fmaxf(mx, __shfl_xor(mx, 4));
  mx = fmaxf(mx, __shfl_xor(mx, 8));
  float e = (j < 12) ? __expf(logit - mx) : 0.f;
  float s = e;
  s += __shfl_xor(s, 1);
  s += __shfl_xor(s, 2);
  s += __shfl_xor(s, 4);
  s += __shfl_xor(s, 8);
  float aww = e / s;

  unsigned packk[8];
  #pragma unroll
  for (int k = 0; k < 8; k++) packk[k] = 0;

  if (j < 12){
    int l = j >> 2;
    int Dl  = (l == 0) ? 24 : ((l == 1) ? 12 : 6);
    int lst = (l == 0) ? 0  : ((l == 1) ? L1START : L2START);
    const float* op = offaw + (size_t)r * 384 + head * 36 + j * 3;
    float od = op[0], ox = op[1], oy = op[2];
    float fDl = (float)Dl;
    float pd = refd * fDl + od - 0.5f;
    float px = refx * fDl + ox - 0.5f;
    float py = refy * fDl + oy - 0.5f;
    float fld = floorf(pd), flx = floorf(px), fly = floorf(py);
    float fd = pd - fld, fx = px - flx, fy = py - fly;
    int d0 = (int)fld, x0 = (int)flx, y0 = (int)fly;
    float wz[2] = {(1.f - fd) * aww, fd * aww};
    float wy[2] = {1.f - fy, fy};
    float wx[2] = {1.f - fx, fx};
    int rowbase = b * NTOK + lst;
    #pragma unroll
    for (int k = 0; k < 8; k++){
      int cz = k >> 2, cy = (k >> 1) & 1, cx = k & 1;
      int di = d0 + cz, yi = y0 + cy, xi = x0 + cx;
      bool valid = (di >= 0) & (di < Dl) & (yi >= 0) & (yi < Dl) & (xi >= 0) & (xi < Dl);
      int dc = min(max(di, 0), Dl - 1);
      int yc = min(max(yi, 0), Dl - 1);
      int xc = min(max(xi, 0), Dl - 1);
      float wgt = valid ? wz[cz] * wy[cy] * wx[cx] : 0.f;
      unsigned row = (unsigned)(rowbase + (dc * Dl + yc) * Dl + xc);  // < 32768
      packk[k] = ((unsigned)f2bf(wgt) << 16) | row;
    }
  }

  unsigned h64 = (unsigned)__builtin_amdgcn_readfirstlane(head) * 64u;
  const unsigned short* vbase = value + h64;
  float acc0 = 0.f, acc1 = 0.f, acc2 = 0.f, acc3 = 0.f;
  #pragma unroll
  for (int jj = 0; jj < 12; jj++){
    #pragma unroll
    for (int k = 0; k < 8; k++){
      unsigned pk = (unsigned)__builtin_amdgcn_readlane((int)packk[k], jj);
      float sw = __uint_as_float(pk & 0xFFFF0000u);   // bf16 weight in high half
      unsigned srow = pk & 0x7FFFu;
      unsigned short raw = vbase[(size_t)srow * 384u + lane];
      float v = __uint_as_float(((unsigned)raw) << 16);
      int slot = k & 3;
      if (slot == 0) acc0 = fmaf(sw, v, acc0);
      else if (slot == 1) acc1 = fmaf(sw, v, acc1);
      else if (slot == 2) acc2 = fmaf(sw, v, acc2);
      else acc3 = fmaf(sw, v, acc3);
    }
  }
  float acc = (acc0 + acc1) + (acc2 + acc3);
  msout[(size_t)r * DIM + h64 + lane] = f2bf(acc);
}

// depthwise 3x3x3 SAME conv per level segment + exact GELU; bf16 output (feeds fc2 GEMM)
__global__ void k_dwconv_gelu(const float* __restrict__ h, const float* __restrict__ dww,
                              const float* __restrict__ dwb, unsigned short* __restrict__ h2){
  int gid = blockIdx.x * blockDim.x + threadIdx.x;
  if (gid >= ROWS * HID) return;
  int c = gid % HID;
  int r = gid / HID;
  int b = r / NTOK, t = r - b*NTOK;
  int base, DL;
  if (t < L1START){ base = 0; DL = 24; }
  else if (t < L2START){ base = L1START; DL = 12; }
  else { base = L2START; DL = 6; }
  int i = t - base;
  int hw = DL * DL;
  int dd = i / hw; int rem = i - dd*hw; int yy = rem / DL; int xx = rem - yy*DL;
  float acc = 0.f;
  #pragma unroll
  for (int kz = 0; kz < 3; kz++){
    int nd = dd + kz - 1; if (nd < 0 || nd >= DL) continue;
    #pragma unroll
    for (int ky = 0; ky < 3; ky++){
      int ny = yy + ky - 1; if (ny < 0 || ny >= DL) continue;
      #pragma unroll
      for (int kx = 0; kx < 3; kx++){
        int nx = xx + kx - 1; if (nx < 0 || nx >= DL) continue;
        int nt = base + (nd * DL + ny) * DL + nx;
        acc += h[((size_t)(b*NTOK + nt)) * HID + c] * dww[((kz*3 + ky)*3 + kx) * HID + c];
      }
    }
  }
  acc += dwb[c];
  float g = 0.5f * acc * (1.f + erff(acc * 0.70710678118654752440f));
  h2[(size_t)r * HID + c] = f2bf(g);
}

extern "C" void kernel_launch(void* const* d_in, const int* in_sizes, int n_in,
                              void* d_out, int out_size, void* d_ws, size_t ws_size,
                              hipStream_t stream){
  const float* query = (const float*)d_in[0];
  const float* feat  = (const float*)d_in[2];
  const float* qnw = (const float*)d_in[8],  *qnb = (const float*)d_in[9];
  const float* fnw = (const float*)d_in[10], *fnb = (const float*)d_in[11];
  const float* eqw = (const float*)d_in[12], *eqb = (const float*)d_in[13];
  const float* efw = (const float*)d_in[14], *efb = (const float*)d_in[15];
  const float* ffw = (const float*)d_in[16], *ffb = (const float*)d_in[17];
  const float* off_w = (const float*)d_in[18], *off_b = (const float*)d_in[19];
  const float* aw_w  = (const float*)d_in[20], *aw_b  = (const float*)d_in[21];
  const float* val_w = (const float*)d_in[22], *val_b = (const float*)d_in[23];
  const float* out_w = (const float*)d_in[24], *out_b = (const float*)d_in[25];
  const float* fc1_w = (const float*)d_in[26], *fc1_b = (const float*)d_in[27];
  const float* dw_w  = (const float*)d_in[28], *dw_b  = (const float*)d_in[29];
  const float* fc2_w = (const float*)d_in[30], *fc2_b = (const float*)d_in[31];
  float* out = (float*)d_out;

  // workspace layout (~171 MB with lifetime-disjoint aliasing)
  char* p = (char*)d_ws;
  float* qn             = (float*)p;          p += (size_t)ROWS*384*4;  // qn; later h2
  unsigned short* aq    = (unsigned short*)p; p += (size_t)MPAD*384*2;  // aq -> t
  unsigned short* af    = (unsigned short*)p; p += (size_t)MPAD*384*2;  // af -> msout
  unsigned short* value = (unsigned short*)p; p += (size_t)ROWS*384*2;  // value; later h
  float* offaw          = (float*)p;          p += (size_t)ROWS*384*4;  // off+aw; later y1
  unsigned short* wt_val   = (unsigned short*)p; p += (size_t)384*384*2;
  unsigned short* wt_offaw = (unsigned short*)p; p += (size_t)384*384*2;
  unsigned short* wt_out   = (unsigned short*)p; p += (size_t)384*384*2;
  unsigned short* wt_fc1   = (unsigned short*)p; p += (size_t)128*384*2;
  unsigned short* wt_fc2   = (unsigned short*)p; p += (size_t)384*96*2;
  float* offaw_b           = (float*)p;          p += (size_t)384*4;
  // aliases (lifetime-disjoint)
  unsigned short* t_buf  = aq;                    // MPAD*384 bf16
  unsigned short* msout  = af;                    // MPAD*384 bf16
  float* y1              = offaw;                 // ROWS*384 f32 (offaw dead post-msdeform)
  float* h_buf           = (float*)value;         // ROWS*96 f32 (value dead post-msdeform)
  unsigned short* h2_buf = (unsigned short*)qn;   // MPAD*96 bf16 (qn dead post-out-GEMM)

  k_cvt_all<<<(528768 + 255)/256, 256, 0, stream>>>(val_w, off_w, aw_w, out_w, fc1_w, fc2_w,
                                                    off_b, aw_b,
                                                    wt_val, wt_offaw, wt_out, wt_fc1, wt_fc2,
                                                    offaw_b);

  int lnBlocks = ROWS / 4;
  k_ln_front<<<lnBlocks, 256, 0, stream>>>(query, feat, qnw, qnb, fnw, fnb,
                                           eqw, eqb, efw, efb, qn, aq, af);

  dim3 gN384(3, MPAD/128), gN128(1, MPAD/128);

  // value = bf16(af @ val_w + val_b)
  k_gemm<true ><<<gN384, 256, 0, stream>>>(af, wt_val, val_b, nullptr, value, ROWS, 384, 384);
  // off(0:216) + aw logits(256:328) = aq @ [off_w|aw_w] + [off_b|aw_b]
  k_gemm<false><<<gN384, 256, 0, stream>>>(aq, wt_offaw, offaw_b, nullptr, offaw, ROWS, 384, 384);
  // deformable sampling -> msout (bf16; af dead)
  k_msdeform<<<ROWS, 384, 0, stream>>>(value, offaw, msout);
  // y1 = msout @ out_w + out_b + qn   (offaw dead)
  k_gemm<false><<<gN384, 256, 0, stream>>>(msout, wt_out, out_b, qn, y1, ROWS, 384, 384);
  // t = LN(y1, ffn_norm)  (aq dead)
  k_ln<<<lnBlocks, 256, 0, stream>>>(y1, ffw, ffb, t_buf);
  // h = t @ fc1_w + fc1_b   (value dead)
  k_gemm<false><<<gN128, 256, 0, stream>>>(t_buf, wt_fc1, fc1_b, nullptr, h_buf, ROWS, 96, 384);
  // h2 = gelu(dwconv(h))    (qn dead)
  k_dwconv_gelu<<<(ROWS * HID + 255)/256, 256, 0, stream>>>(h_buf, dw_w, dw_b, h2_buf);
  // out = h2 @ fc2_w + fc2_b + y1
  k_gemm<false><<<gN384, 256, 0, stream>>>(h2_buf, wt_fc2, fc2_b, y1, out, ROWS, 384, 96);
}

// Round 5
// 610.134 us; speedup vs baseline: 2.7572x; 1.0496x over previous
//
#include <hip/hip_runtime.h>
#include <hip/hip_fp16.h>
#include <cstdint>
#include <cstddef>

// Problem constants (fixed by the reference file)
#define DIM    384
#define HEADS  6
#define HD     64
#define NTOK   15768
#define NMID   1728
#define BATCH  2
#define ROWS   (BATCH*NTOK)   // 31536
#define MPAD   31616          // 247*128  (GEMM row-tile padding)
#define L1START 13824         // 8*NMID
#define L2START 15552         // 9*NMID
#define HID    96
#define VROWS  (ROWS + 8)     // +pad row for x==Dl spill (weight 0)
#define VSLAB  ((size_t)VROWS * 64)   // per-head slab in __half elements

typedef __attribute__((ext_vector_type(8))) short short8;   // 8 bf16 (4 VGPRs)
typedef __attribute__((ext_vector_type(4))) float floatx4;  // MFMA accumulator

__device__ __forceinline__ unsigned short f2bf(float x){
  unsigned u = __float_as_uint(x);
  unsigned r = (u + 0x7FFFu + ((u >> 16) & 1u)) >> 16;   // round-to-nearest-even
  return (unsigned short)r;
}

__device__ __forceinline__ float wave_sum(float v){
  #pragma unroll
  for (int o = 32; o; o >>= 1) v += __shfl_xor(v, o, 64);
  return v;
}

// LayerNorm over 384 channels held as 6 regs/lane (c = j*64 + lane)
__device__ __forceinline__ void ln384(const float* x, float* y,
                                      const float* __restrict__ w,
                                      const float* __restrict__ b, int lane){
  float s = 0.f;
  #pragma unroll
  for (int j = 0; j < 6; j++) s += x[j];
  s = wave_sum(s);
  float m = s * (1.f/384.f);
  float v = 0.f;
  #pragma unroll
  for (int j = 0; j < 6; j++){ float d = x[j] - m; v += d*d; }
  v = wave_sum(v) * (1.f/384.f);
  float rs = rsqrtf(v + 1e-6f);
  #pragma unroll
  for (int j = 0; j < 6; j++){
    int c = j*64 + lane;
    y[j] = (x[j] - m) * rs * w[c] + b[c];
  }
}

// q = query (+feat on mid segment); qn=LN(q) fp32; aq=LN(qn) bf16; af=LN(LN(q,fnorm)) bf16
__global__ void k_ln_front(const float* __restrict__ query, const float* __restrict__ feat,
                           const float* __restrict__ qw,  const float* __restrict__ qb,
                           const float* __restrict__ fw,  const float* __restrict__ fb,
                           const float* __restrict__ eqw, const float* __restrict__ eqb,
                           const float* __restrict__ efw, const float* __restrict__ efb,
                           float* __restrict__ qn, unsigned short* __restrict__ aq,
                           unsigned short* __restrict__ af){
  int wid = blockIdx.x * (blockDim.x >> 6) + (threadIdx.x >> 6);
  if (wid >= ROWS) return;
  int lane = threadIdx.x & 63;
  int b = wid / NTOK, t = wid - b*NTOK;
  const float* qp = query + (size_t)wid * DIM;
  float x[6];
  #pragma unroll
  for (int j = 0; j < 6; j++) x[j] = qp[j*64 + lane];
  if (t >= L1START && t < L2START){
    const float* fp = feat + ((size_t)b*NMID + (t - L1START)) * DIM;
    #pragma unroll
    for (int j = 0; j < 6; j++) x[j] += fp[j*64 + lane];
  }
  float y[6], z[6];
  ln384(x, y, qw, qb, lane);                 // qn
  {
    float* o = qn + (size_t)wid * DIM;
    #pragma unroll
    for (int j = 0; j < 6; j++) o[j*64 + lane] = y[j];
  }
  ln384(y, z, eqw, eqb, lane);               // aq = LN(qn)
  {
    unsigned short* o = aq + (size_t)wid * DIM;
    #pragma unroll
    for (int j = 0; j < 6; j++) o[j*64 + lane] = f2bf(z[j]);
  }
  ln384(x, y, fw, fb, lane);                 // fn
  ln384(y, z, efw, efb, lane);               // af = LN(fn)
  {
    unsigned short* o = af + (size_t)wid * DIM;
    #pragma unroll
    for (int j = 0; j < 6; j++) o[j*64 + lane] = f2bf(z[j]);
  }
}

// plain LN: out_bf16 = LN(in_f32, w, b)
__global__ void k_ln(const float* __restrict__ in, const float* __restrict__ w,
                     const float* __restrict__ b, unsigned short* __restrict__ out){
  int wid = blockIdx.x * (blockDim.x >> 6) + (threadIdx.x >> 6);
  if (wid >= ROWS) return;
  int lane = threadIdx.x & 63;
  float x[6], y[6];
  const float* p = in + (size_t)wid * DIM;
  #pragma unroll
  for (int j = 0; j < 6; j++) x[j] = p[j*64 + lane];
  ln384(x, y, w, b, lane);
  unsigned short* o = out + (size_t)wid * DIM;
  #pragma unroll
  for (int j = 0; j < 6; j++) o[j*64 + lane] = f2bf(y[j]);
}

// One-shot weight convert+transpose for all GEMMs + combined off/aw bias.
__global__ void k_cvt_all(const float* __restrict__ val_w, const float* __restrict__ off_w,
                          const float* __restrict__ aw_w,  const float* __restrict__ out_w,
                          const float* __restrict__ fc1_w, const float* __restrict__ fc2_w,
                          const float* __restrict__ off_b, const float* __restrict__ aw_b,
                          unsigned short* __restrict__ wt_val, unsigned short* __restrict__ wt_offaw,
                          unsigned short* __restrict__ wt_out, unsigned short* __restrict__ wt_fc1,
                          unsigned short* __restrict__ wt_fc2, float* __restrict__ offaw_b){
  int id = blockIdx.x * blockDim.x + threadIdx.x;
  if (id < 147456){                                   // val: K=384, Npad=384
    int n = id / 384, k = id - n*384;
    wt_val[id] = f2bf(val_w[(size_t)k*384 + n]);
  } else if (id < 294912){                            // off(216)+aw(72@256): K=384, Npad=384
    int i = id - 147456;
    int n = i / 384, k = i - n*384;
    float v = 0.f;
    if (n < 216) v = off_w[(size_t)k*216 + n];
    else if (n >= 256 && n < 328) v = aw_w[(size_t)k*72 + (n-256)];
    wt_offaw[i] = f2bf(v);
  } else if (id < 442368){                            // out: K=384, Npad=384
    int i = id - 294912;
    int n = i / 384, k = i - n*384;
    wt_out[i] = f2bf(out_w[(size_t)k*384 + n]);
  } else if (id < 491520){                            // fc1: K=384, N=96, Npad=128
    int i = id - 442368;
    int n = i / 384, k = i - n*384;
    wt_fc1[i] = f2bf((n < 96) ? fc1_w[(size_t)k*96 + n] : 0.f);
  } else if (id < 528384){                            // fc2: K=96, Npad=384
    int i = id - 491520;
    int n = i / 96, k = i - n*96;
    wt_fc2[i] = f2bf(fc2_w[(size_t)k*384 + n]);
  } else if (id < 528768){                            // combined off/aw bias [384]
    int n = id - 528384;
    float v = 0.f;
    if (n < 216) v = off_b[n];
    else if (n >= 256 && n < 328) v = aw_b[n-256];
    offaw_b[n] = v;
  }
}

// bf16 MFMA GEMM: C[M,N] = A[Mpad,K]bf16 @ Wt[Npad,K]bf16^T + bias (+R).
// 128x128 tile, BK=32, 256 threads. Staging via global_load_lds width=16.
// OUTMODE: 0 = f32 row-major; 1 = bf16 row-major; 2 = f16 value-layout [head][row][64]
template<int OUTMODE>
__global__ __launch_bounds__(256) void k_gemm(
    const unsigned short* __restrict__ A,
    const unsigned short* __restrict__ Wt,
    const float* __restrict__ bias,
    const float* __restrict__ R,
    void* __restrict__ Cv,
    int M, int N, int K){
  __shared__ __align__(16) unsigned short As[128*32];
  __shared__ __align__(16) unsigned short Bs[128*32];
  int tid = threadIdx.x;
  int w = tid >> 6, lane = tid & 63;
  int m0 = blockIdx.y * 128, n0 = blockIdx.x * 128;
  int m_off = (w & 1) * 64, n_off = (w >> 1) * 64;

  floatx4 acc[4][4] = {};

  int sr = lane >> 2;          // row within 16-row staging chunk
  int sc = (lane & 3) * 8;     // bf16-element offset within row (16B granules)
  int lrow = lane & 15;        // MFMA row/col within 16
  int kq = (lane >> 4) * 8;    // k-offset of this lane's 8-element fragment

  for (int k0 = 0; k0 < K; k0 += 32){
    #pragma unroll
    for (int s = 0; s < 2; s++){
      int c = w * 2 + s;       // chunk 0..7 (16 rows each)
      const unsigned short* ga = A  + (size_t)(m0 + c*16 + sr) * K + k0 + sc;
      __builtin_amdgcn_global_load_lds(
          (const __attribute__((address_space(1))) void*)ga,
          (__attribute__((address_space(3))) void*)(As + c*512), 16, 0, 0);
      const unsigned short* gb = Wt + (size_t)(n0 + c*16 + sr) * K + k0 + sc;
      __builtin_amdgcn_global_load_lds(
          (const __attribute__((address_space(1))) void*)gb,
          (__attribute__((address_space(3))) void*)(Bs + c*512), 16, 0, 0);
    }
    __syncthreads();
    short8 afr[4], bfr[4];
    #pragma unroll
    for (int i = 0; i < 4; i++)
      afr[i] = *(const short8*)(As + (m_off + i*16 + lrow)*32 + kq);
    #pragma unroll
    for (int j = 0; j < 4; j++)
      bfr[j] = *(const short8*)(Bs + (n_off + j*16 + lrow)*32 + kq);
    #pragma unroll
    for (int i = 0; i < 4; i++)
      #pragma unroll
      for (int j = 0; j < 4; j++)
        acc[i][j] = __builtin_amdgcn_mfma_f32_16x16x32_bf16(afr[i], bfr[j], acc[i][j], 0, 0, 0);
    __syncthreads();
  }

  // epilogue: C/D layout col = lane&15, row = (lane>>4)*4 + reg
  int cn = n0 + n_off + lrow;
  int rbase = m0 + m_off + (lane >> 4) * 4;
  #pragma unroll
  for (int j = 0; j < 4; j++){
    int n = cn + j*16;
    if (n >= N) continue;
    float bj = bias[n];
    #pragma unroll
    for (int i = 0; i < 4; i++){
      int mb = rbase + i*16;
      #pragma unroll
      for (int r = 0; r < 4; r++){
        int m = mb + r;
        if (m < M){
          float v = acc[i][j][r] + bj;
          if (R) v += R[(size_t)m * N + n];
          if (OUTMODE == 0)      ((float*)Cv)[(size_t)m * N + n] = v;
          else if (OUTMODE == 1) ((unsigned short*)Cv)[(size_t)m * N + n] = f2bf(v);
          else { // f16 value layout: [head = n>>6][row = m][ch = n&63]
            ((__half*)Cv)[(size_t)(n >> 6) * VSLAB + (size_t)m * 64 + (n & 63)] =
                __float2half_rn(v);
          }
        }
      }
    }
  }
}

// Multi-scale deformable sampling v3: one block per (b,token) [XCD-swizzled], one wave
// per head. value is f16 in [head][row][64] layout; the two x-corners of a trilinear
// pair are ADJACENT 128 B rows, so one dword load per lane fetches 2 corners x 2 ch
// (lanes 0-31 = row x, lanes 32-63 = row x+1; voffset = lane*4, saddr per pair).
// Per pair: 2 readlane + weight-select cndmask + v_pk_fma_f16. f16 partials flushed
// to f32 every 4 points (4-term f16 chains).
__global__ __launch_bounds__(384) void k_msdeform(const __half* __restrict__ vt,
                                                  const float* __restrict__ offaw,
                                                  unsigned short* __restrict__ msout){
  int bx = blockIdx.x;
  int r = (bx & 7) * (ROWS/8) + (bx >> 3);   // XCD-aware swizzle
  int head = threadIdx.x >> 6;
  int lane = threadIdx.x & 63;
  int b = r / NTOK, t = r - b*NTOK;

  int base, DL0;
  if (t < L1START){ base = 0; DL0 = 24; }
  else if (t < L2START){ base = L1START; DL0 = 12; }
  else { base = L2START; DL0 = 6; }
  int i = t - base;
  int hw = DL0 * DL0;
  int dd = i / hw; int rem = i - dd*hw; int yy = rem / DL0; int xx = rem - yy*DL0;
  float refd = (dd + 0.5f) / (float)DL0;
  float refy = (yy + 0.5f) / (float)DL0;
  float refx = (xx + 0.5f) / (float)DL0;

  int j = lane;  // point index (j < 12 active)

  float logit = (j < 12) ? offaw[(size_t)r * 384 + 256 + head * 12 + j] : -1e30f;
  float mx = logit;
  mx = fmaxf(mx, __shfl_xor(mx, 1));
  mx = fmaxf(mx, __shfl_xor(mx, 2));
  mx = fmaxf(mx, __shfl_xor(mx, 4));
  mx = fmaxf(mx, __shfl_xor(mx, 8));
  float e = (j < 12) ? __expf(logit - mx) : 0.f;
  float s = e;
  s += __shfl_xor(s, 1);
  s += __shfl_xor(s, 2);
  s += __shfl_xor(s, 4);
  s += __shfl_xor(s, 8);
  float aww = e / s;

  // per-point descriptors: 4 (cz,cy) pairs, each = {row of x-lo corner, f16x2 (wlo,whi)}
  int rowk[4] = {0,0,0,0};
  int wgtk[4] = {0,0,0,0};

  if (j < 12){
    int l = j >> 2;
    int Dl  = (l == 0) ? 24 : ((l == 1) ? 12 : 6);
    int lst = (l == 0) ? 0  : ((l == 1) ? L1START : L2START);
    const float* op = offaw + (size_t)r * 384 + head * 36 + j * 3;
    float od = op[0], ox = op[1], oy = op[2];
    float fDl = (float)Dl;
    float pd = refd * fDl + od - 0.5f;
    float px = refx * fDl + ox - 0.5f;
    float py = refy * fDl + oy - 0.5f;
    float fld = floorf(pd), flx = floorf(px), fly = floorf(py);
    float fd = pd - fld, fx = px - flx, fy = py - fly;
    int d0 = (int)fld, x0 = (int)flx, y0 = (int)fly;
    float wz2[2] = {(1.f - fd) * aww, fd * aww};
    float wy2[2] = {1.f - fy, fy};
    // x-pair mapping: load rows (rs, rs+1); weights assigned per clamp case
    int rs = min(max(x0, 0), Dl - 1);
    float wlo_x = (rs == x0) ? (1.f - fx) : ((rs == x0 + 1) ? fx : 0.f);
    float whi_x = ((rs == x0) && (x0 + 1 < Dl)) ? fx : 0.f;
    int rowbase = b * NTOK + lst;
    #pragma unroll
    for (int p = 0; p < 4; p++){
      int cz = p >> 1, cy = p & 1;
      int di = d0 + cz, yi = y0 + cy;
      bool vzy = (di >= 0) & (di < Dl) & (yi >= 0) & (yi < Dl);
      float wp = vzy ? wz2[cz] * wy2[cy] : 0.f;
      int dc = min(max(di, 0), Dl - 1);
      int yc = min(max(yi, 0), Dl - 1);
      rowk[p] = rowbase + (dc * Dl + yc) * Dl + rs;
      __half2 wh = __floats2half2_rn(wp * wlo_x, wp * whi_x);
      wgtk[p] = *(int*)&wh;
    }
  }

  int head_u = __builtin_amdgcn_readfirstlane(head);
  const __half2* vh = (const __half2*)(vt + (size_t)head_u * VSLAB);
  unsigned laneHi = lane & 32;           // loop-invariant select

  __half2 hz; *(int*)&hz = 0;
  __half2 a0 = hz, a1 = hz, a2 = hz, a3 = hz;
  float fLo = 0.f, fHi = 0.f;

  #pragma unroll
  for (int seg = 0; seg < 3; seg++){
    #pragma unroll
    for (int q = 0; q < 4; q++){
      int jj = seg * 4 + q;
      #pragma unroll
      for (int p = 0; p < 4; p++){
        int srow = __builtin_amdgcn_readlane(rowk[p], jj);
        int swp  = __builtin_amdgcn_readlane(wgtk[p], jj);
        unsigned wlo2 = (unsigned)(swp & 0xFFFF) * 0x00010001u;            // dup lo f16
        unsigned whi2 = ((unsigned)swp & 0xFFFF0000u) | ((unsigned)swp >> 16); // dup hi
        unsigned w2u = laneHi ? whi2 : wlo2;
        __half2 w2 = *(__half2*)&w2u;
        __half2 v = vh[(size_t)((unsigned)srow << 5) + (unsigned)lane];
        if (p == 0)      a0 = __hfma2(w2, v, a0);
        else if (p == 1) a1 = __hfma2(w2, v, a1);
        else if (p == 2) a2 = __hfma2(w2, v, a2);
        else             a3 = __hfma2(w2, v, a3);
      }
    }
    float2 f0 = __half22float2(a0), f1 = __half22float2(a1);
    float2 f2 = __half22float2(a2), f3 = __half22float2(a3);
    fLo += (f0.x + f1.x) + (f2.x + f3.x);
    fHi += (f0.y + f1.y) + (f2.y + f3.y);
    a0 = a1 = a2 = a3 = hz;
  }

  // lanes i and i+32 hold the x-lo / x-hi halves of the same channel pair
  float sLo = fLo + __shfl_xor(fLo, 32);
  float sHi = fHi + __shfl_xor(fHi, 32);
  if (lane < 32){
    unsigned packed = ((unsigned)f2bf(sHi) << 16) | (unsigned)f2bf(sLo);
    *(unsigned*)(msout + (size_t)r * DIM + head * 64 + lane * 2) = packed;
  }
}

// depthwise 3x3x3 SAME conv per level segment + exact GELU; bf16 output (feeds fc2 GEMM)
__global__ void k_dwconv_gelu(const float* __restrict__ h, const float* __restrict__ dww,
                              const float* __restrict__ dwb, unsigned short* __restrict__ h2){
  int gid = blockIdx.x * blockDim.x + threadIdx.x;
  if (gid >= ROWS * HID) return;
  int c = gid % HID;
  int r = gid / HID;
  int b = r / NTOK, t = r - b*NTOK;
  int base, DL;
  if (t < L1START){ base = 0; DL = 24; }
  else if (t < L2START){ base = L1START; DL = 12; }
  else { base = L2START; DL = 6; }
  int i = t - base;
  int hw = DL * DL;
  int dd = i / hw; int rem = i - dd*hw; int yy = rem / DL; int xx = rem - yy*DL;
  float acc = 0.f;
  #pragma unroll
  for (int kz = 0; kz < 3; kz++){
    int nd = dd + kz - 1; if (nd < 0 || nd >= DL) continue;
    #pragma unroll
    for (int ky = 0; ky < 3; ky++){
      int ny = yy + ky - 1; if (ny < 0 || ny >= DL) continue;
      #pragma unroll
      for (int kx = 0; kx < 3; kx++){
        int nx = xx + kx - 1; if (nx < 0 || nx >= DL) continue;
        int nt = base + (nd * DL + ny) * DL + nx;
        acc += h[((size_t)(b*NTOK + nt)) * HID + c] * dww[((kz*3 + ky)*3 + kx) * HID + c];
      }
    }
  }
  acc += dwb[c];
  float g = 0.5f * acc * (1.f + erff(acc * 0.70710678118654752440f));
  h2[(size_t)r * HID + c] = f2bf(g);
}

extern "C" void kernel_launch(void* const* d_in, const int* in_sizes, int n_in,
                              void* d_out, int out_size, void* d_ws, size_t ws_size,
                              hipStream_t stream){
  const float* query = (const float*)d_in[0];
  const float* feat  = (const float*)d_in[2];
  const float* qnw = (const float*)d_in[8],  *qnb = (const float*)d_in[9];
  const float* fnw = (const float*)d_in[10], *fnb = (const float*)d_in[11];
  const float* eqw = (const float*)d_in[12], *eqb = (const float*)d_in[13];
  const float* efw = (const float*)d_in[14], *efb = (const float*)d_in[15];
  const float* ffw = (const float*)d_in[16], *ffb = (const float*)d_in[17];
  const float* off_w = (const float*)d_in[18], *off_b = (const float*)d_in[19];
  const float* aw_w  = (const float*)d_in[20], *aw_b  = (const float*)d_in[21];
  const float* val_w = (const float*)d_in[22], *val_b = (const float*)d_in[23];
  const float* out_w = (const float*)d_in[24], *out_b = (const float*)d_in[25];
  const float* fc1_w = (const float*)d_in[26], *fc1_b = (const float*)d_in[27];
  const float* dw_w  = (const float*)d_in[28], *dw_b  = (const float*)d_in[29];
  const float* fc2_w = (const float*)d_in[30], *fc2_b = (const float*)d_in[31];
  float* out = (float*)d_out;

  // workspace layout (~171 MB with lifetime-disjoint aliasing)
  char* p = (char*)d_ws;
  float* qn             = (float*)p;          p += (size_t)ROWS*384*4;  // qn; later h2
  unsigned short* aq    = (unsigned short*)p; p += (size_t)MPAD*384*2;  // aq -> t
  unsigned short* af    = (unsigned short*)p; p += (size_t)MPAD*384*2;  // af -> msout
  __half* value_t       = (__half*)p;         p += (size_t)HEADS*VSLAB*2; // value; later h
  float* offaw          = (float*)p;          p += (size_t)ROWS*384*4;  // off+aw; later y1
  unsigned short* wt_val   = (unsigned short*)p; p += (size_t)384*384*2;
  unsigned short* wt_offaw = (unsigned short*)p; p += (size_t)384*384*2;
  unsigned short* wt_out   = (unsigned short*)p; p += (size_t)384*384*2;
  unsigned short* wt_fc1   = (unsigned short*)p; p += (size_t)128*384*2;
  unsigned short* wt_fc2   = (unsigned short*)p; p += (size_t)384*96*2;
  float* offaw_b           = (float*)p;          p += (size_t)384*4;
  // aliases (lifetime-disjoint)
  unsigned short* t_buf  = aq;                    // MPAD*384 bf16
  unsigned short* msout  = af;                    // MPAD*384 bf16
  float* y1              = offaw;                 // ROWS*384 f32 (offaw dead post-msdeform)
  float* h_buf           = (float*)value_t;       // ROWS*96 f32 (value dead post-msdeform)
  unsigned short* h2_buf = (unsigned short*)qn;   // MPAD*96 bf16 (qn dead post-out-GEMM)

  k_cvt_all<<<(528768 + 255)/256, 256, 0, stream>>>(val_w, off_w, aw_w, out_w, fc1_w, fc2_w,
                                                    off_b, aw_b,
                                                    wt_val, wt_offaw, wt_out, wt_fc1, wt_fc2,
                                                    offaw_b);

  int lnBlocks = ROWS / 4;
  k_ln_front<<<lnBlocks, 256, 0, stream>>>(query, feat, qnw, qnb, fnw, fnb,
                                           eqw, eqb, efw, efb, qn, aq, af);

  dim3 gN384(3, MPAD/128), gN128(1, MPAD/128);

  // value (f16, [head][row][64]) = af @ val_w + val_b
  k_gemm<2><<<gN384, 256, 0, stream>>>(af, wt_val, val_b, nullptr, value_t, ROWS, 384, 384);
  // off(0:216) + aw logits(256:328) = aq @ [off_w|aw_w] + [off_b|aw_b]
  k_gemm<0><<<gN384, 256, 0, stream>>>(aq, wt_offaw, offaw_b, nullptr, offaw, ROWS, 384, 384);
  // deformable sampling -> msout (bf16; af dead)
  k_msdeform<<<ROWS, 384, 0, stream>>>(value_t, offaw, msout);
  // y1 = msout @ out_w + out_b + qn   (offaw dead)
  k_gemm<0><<<gN384, 256, 0, stream>>>(msout, wt_out, out_b, qn, y1, ROWS, 384, 384);
  // t = LN(y1, ffn_norm)  (aq dead)
  k_ln<<<lnBlocks, 256, 0, stream>>>(y1, ffw, ffb, t_buf);
  // h = t @ fc1_w + fc1_b   (value dead)
  k_gemm<0><<<gN128, 256, 0, stream>>>(t_buf, wt_fc1, fc1_b, nullptr, h_buf, ROWS, 96, 384);
  // h2 = gelu(dwconv(h))    (qn dead)
  k_dwconv_gelu<<<(ROWS * HID + 255)/256, 256, 0, stream>>>(h_buf, dw_w, dw_b, h2_buf);
  // out = h2 @ fc2_w + fc2_b + y1
  k_gemm<0><<<gN384, 256, 0, stream>>>(h2_buf, wt_fc2, fc2_b, y1, out, ROWS, 384, 96);
}